// Round 7
// baseline (1802.677 us; speedup 1.0000x reference)
//
#include <hip/hip_runtime.h>
#include <stdint.h>

#define N_ATOM 100000
#define M_NBR 12
#define A_FEA 128
#define E_FEA 64
#define KDIM 320
#define GDIM 256
#define ROWS (N_ATOM*M_NBR)
#define BN_EPS 1e-5f

typedef unsigned short u16;
typedef unsigned int u32;
typedef __attribute__((ext_vector_type(8))) short short8;
typedef __attribute__((ext_vector_type(4))) float f32x4;
typedef __attribute__((ext_vector_type(4))) unsigned int u32x4;

// ---- stats slot indices (floats) ----
#define S_BN1SUM 0
#define S_BN1SSQ 256
#define S_S1 512
#define S_T1 768
#define S_BN2SUM 1024
#define S_BN2SSQ 1152
#define S_S2 1280
#define S_T2 1408
#define STATS_F32 1536

// ---- workspace layout ----
#define WPQ_OFF 0
#define W3T_OFF 131072
#define WSK_OFF 163840
#define STATS_OFF 196608
#define P_OFF 202752
#define PQ_BYTES ((size_t)N_ATOM*256*2)            // 51,200,000
#define Q_OFF (P_OFF + PQ_BYTES)
#define NEED_FAST3 (P_OFF + 2*PQ_BYTES)            // ~102.6 MB

__device__ __forceinline__ u16 f2bf(float x) {
    union { float f; u32 u; } v; v.f = x;
    u32 r = v.u + 0x7FFFu + ((v.u >> 16) & 1u);
    return (u16)(r >> 16);
}
__device__ __forceinline__ u16 f2bf_u(u32 u) {
    return (u16)((u + 0x7FFFu + ((u >> 16) & 1u)) >> 16);
}
__device__ __forceinline__ float bflo(u32 x) { return __uint_as_float(x << 16); }
__device__ __forceinline__ float bfhi(u32 x) { return __uint_as_float(x & 0xFFFF0000u); }
__device__ __forceinline__ float softplus_f(float x) {
    return fmaxf(x, 0.f) + __logf(1.f + __expf(-fabsf(x)));
}
__device__ __forceinline__ float sigmoid_f(float x) {
    return 1.f / (1.f + __expf(-x));
}

// Zero bn accumulators every launch (plain kernel -> always a graph node).
__global__ void zero_stats(float* __restrict__ stats) {
    int t = threadIdx.x;              // 256
    stats[t] = 0.f;
    stats[256 + t] = 0.f;
    stats[1024 + t] = 0.f;
}

__global__ void finalize1(const float* __restrict__ g1, const float* __restrict__ b1,
                          float* __restrict__ stats) {
    int c = threadIdx.x;  // 256
    const float inv_cnt = 1.f / (float)ROWS;
    float mean = stats[S_BN1SUM + c] * inv_cnt;
    float var  = stats[S_BN1SSQ + c] * inv_cnt - mean * mean;
    float iv = rsqrtf(var + BN_EPS);
    float s = g1[c] * iv;
    stats[S_S1 + c] = s;
    stats[S_T1 + c] = fmaf(-mean, s, b1[c]);
}

__global__ void finalize2(const float* __restrict__ g2, const float* __restrict__ b2,
                          float* __restrict__ stats) {
    int c = threadIdx.x;  // 128
    const float inv_cnt = 1.f / (float)N_ATOM;
    float mean = stats[S_BN2SUM + c] * inv_cnt;
    float var  = stats[S_BN2SSQ + c] * inv_cnt - mean * mean;
    float iv = rsqrtf(var + BN_EPS);
    float s = g2[c] * iv;
    stats[S_S2 + c] = s;
    stats[S_T2 + c] = fmaf(-mean, s, b2[c]);
}

// Pack Wpq (B for P/Q GEMM: 128 x 512), W3T (A-frags of W3^T: 256 x 64),
// Wsk (128 x 128) into MFMA fragment order.
__global__ void prep_pack2(const float* __restrict__ Wfull,
                           const float* __restrict__ Wskip,
                           u16* __restrict__ wpq, u16* __restrict__ w3t,
                           u16* __restrict__ wsk) {
    int tid = blockIdx.x * blockDim.x + threadIdx.x;
    int l = tid & 63, fr = l & 15, fq = l >> 4;
    if (tid < 8192) {
        int ct = (tid >> 6) & 31;
        int kt = tid >> 11;                 // 0..3
        int c = ct * 16 + fr;               // 0..511
        int k0 = kt * 32 + fq * 8;          // 0..127
        u16 tmp[8];
        #pragma unroll
        for (int i = 0; i < 8; ++i) {
            int kk = k0 + i;
            float v = (c < 256) ? Wfull[kk * GDIM + c]
                                : Wfull[(128 + kk) * GDIM + (c - 256)];
            tmp[i] = f2bf(v);
        }
        uint4 pk;
        pk.x = (u32)tmp[0] | ((u32)tmp[1] << 16);
        pk.y = (u32)tmp[2] | ((u32)tmp[3] << 16);
        pk.z = (u32)tmp[4] | ((u32)tmp[5] << 16);
        pk.w = (u32)tmp[6] | ((u32)tmp[7] << 16);
        *reinterpret_cast<uint4*>(&wpq[tid * 8]) = pk;
    } else if (tid < 10240) {
        // W3T A-frag: frag=(kt*16+rt16), elem i -> Wfull[256+kt*32+fq*8+i][rt16*16+fr]
        int t2 = tid - 8192;               // 0..2047
        int frag = t2 >> 6;                // 0..31
        int rt16 = frag & 15, kt = frag >> 4;
        int gcol = rt16 * 16 + fr;
        int k0 = kt * 32 + fq * 8;
        u16 tmp[8];
        #pragma unroll
        for (int i = 0; i < 8; ++i) tmp[i] = f2bf(Wfull[(256 + k0 + i) * GDIM + gcol]);
        uint4 pk;
        pk.x = (u32)tmp[0] | ((u32)tmp[1] << 16);
        pk.y = (u32)tmp[2] | ((u32)tmp[3] << 16);
        pk.z = (u32)tmp[4] | ((u32)tmp[5] << 16);
        pk.w = (u32)tmp[6] | ((u32)tmp[7] << 16);
        *reinterpret_cast<uint4*>(&w3t[t2 * 8]) = pk;
    } else if (tid < 12288) {
        int t3 = tid - 10240;
        int ct = (t3 >> 6) & 7;
        int kt = t3 >> 9;                   // 0..3
        int c = ct * 16 + fr;
        int k0 = kt * 32 + fq * 8;
        u16 tmp[8];
        #pragma unroll
        for (int i = 0; i < 8; ++i) tmp[i] = f2bf(Wskip[(k0 + i) * A_FEA + c]);
        uint4 pk;
        pk.x = (u32)tmp[0] | ((u32)tmp[1] << 16);
        pk.y = (u32)tmp[2] | ((u32)tmp[3] << 16);
        pk.z = (u32)tmp[4] | ((u32)tmp[5] << 16);
        pk.w = (u32)tmp[6] | ((u32)tmp[7] << 16);
        *reinterpret_cast<uint4*>(&wsk[t3 * 8]) = pk;
    }
}

// P[n] = atom_in[n] @ Wfull[0:128];  Q[n] = atom_in[n] @ Wfull[128:256]
__launch_bounds__(256)
__global__ void pq_kernel(const float* __restrict__ atom_in,
                          const u16* __restrict__ wpq,
                          u16* __restrict__ Pb, u16* __restrict__ Qb) {
    __shared__ u16 al[64 * 130];
    const int t = threadIdx.x;
    const int w = t >> 6, l = t & 63, fr = l & 15, fq = l >> 4;
    const int n0 = blockIdx.x * 64;

    #pragma unroll
    for (int it = 0; it < 4; ++it) {
        int c = t + it * 256;         // 0..1023
        int row = c >> 4, seg = c & 15;
        int n = n0 + row;
        uint4 pk = {0u, 0u, 0u, 0u};
        if (n < N_ATOM) {
            const float* src = atom_in + (size_t)n * A_FEA + seg * 8;
            float4 x0 = *reinterpret_cast<const float4*>(src);
            float4 x1 = *reinterpret_cast<const float4*>(src + 4);
            pk.x = (u32)f2bf(x0.x) | ((u32)f2bf(x0.y) << 16);
            pk.y = (u32)f2bf(x0.z) | ((u32)f2bf(x0.w) << 16);
            pk.z = (u32)f2bf(x1.x) | ((u32)f2bf(x1.y) << 16);
            pk.w = (u32)f2bf(x1.z) | ((u32)f2bf(x1.w) << 16);
        }
        *reinterpret_cast<uint4*>(&al[row * 130 + seg * 8]) = pk;
    }
    __syncthreads();

    f32x4 acc[4][8];
    #pragma unroll
    for (int rt = 0; rt < 4; ++rt)
        #pragma unroll
        for (int p = 0; p < 8; ++p)
            acc[rt][p] = (f32x4){0.f,0.f,0.f,0.f};

    for (int kt = 0; kt < 4; ++kt) {
        short8 af[4], bf[8];
        #pragma unroll
        for (int rt = 0; rt < 4; ++rt)
            af[rt] = *reinterpret_cast<const short8*>(
                &al[(rt * 16 + fr) * 130 + kt * 32 + fq * 8]);
        #pragma unroll
        for (int p = 0; p < 8; ++p)
            bf[p] = *reinterpret_cast<const short8*>(
                &wpq[((kt * 32 + w * 8 + p) * 64 + l) * 8]);
        #pragma unroll
        for (int rt = 0; rt < 4; ++rt)
            #pragma unroll
            for (int p = 0; p < 8; ++p)
                acc[rt][p] = __builtin_amdgcn_mfma_f32_16x16x32_bf16(
                    af[rt], bf[p], acc[rt][p], 0, 0, 0);
    }

    #pragma unroll
    for (int p = 0; p < 8; ++p) {
        int col = w * 128 + p * 16 + fr;            // 0..511
        u16* dst = (col < 256) ? Pb : Qb;
        int cc = (col < 256) ? col : (col - 256);
        #pragma unroll
        for (int rt = 0; rt < 4; ++rt)
            #pragma unroll
            for (int j = 0; j < 4; ++j) {
                int n = n0 + rt * 16 + fq * 4 + j;
                if (n < N_ATOM) dst[(size_t)n * 256 + cc] = f2bf(acc[rt][p][j]);
            }
    }
}

// =====================================================================
// Edge kernel v4: transposed MFMA (gated^T = W3^T @ nbr^T), inline f32->bf16
// nbr staging with NT loads, and one-tile-ahead register prefetch of the
// idx->Q gather chain and P rows (T14 async-split).
// tile = 96 edges (8 atoms x 12), 512 threads (8 waves).
// MODE 1: bn1 sum/ssq. MODE 2: act -> m-sum -> out, bn2 stats.
// =====================================================================
#define NTILES_E (ROWS/96)     // 12500
#define GRID_E 2500
#define EPAD 66                // u16 stride of nbr tile rows
#define PPAD2 264              // u16 stride of P rows
#define QPAD2 268              // u16 stride of Q rows
#define ACT2 132               // f32 stride of act rows
#define E_SH (96*EPAD*2)                // 12672
#define P_SH0 E_SH                      // p at +12672 (4224 B)
#define Q_SH0 (E_SH + 8*PPAD2*2)        // q at +16896 (51456 B)
#define SH_TOT (Q_SH0 + 96*QPAD2*2)     // 68352; act overlay 96*132*4=50688 <= 51456

template<int MODE>
__launch_bounds__(512, 4)
__global__ void estage4(const float* __restrict__ nbr_fea,
                        const int* __restrict__ nbr_idx,
                        const u16* __restrict__ w3t,
                        const u16* __restrict__ Pb,
                        const u16* __restrict__ Qb,
                        float* __restrict__ stats,
                        float* __restrict__ out_ns) {
    __shared__ __align__(16) unsigned char shraw[SH_TOT];
    u16* e_lds = (u16*)shraw;
    u16* p_lds = (u16*)(shraw + P_SH0);
    u16* q_lds = (u16*)(shraw + Q_SH0);
    float* act = (float*)(shraw + Q_SH0);
    float* red = (float*)shraw;

    const int t = threadIdx.x;
    const int w = t >> 6, l = t & 63, fr = l & 15, fq = l >> 4;
    const int gbase0 = w * 16 + fq * 4;        // filter col base (rt=0); core = +128

    // Tile-invariant W3^T A-fragments.
    short8 aw[2][2];
    #pragma unroll
    for (int kt = 0; kt < 2; ++kt)
        #pragma unroll
        for (int rt = 0; rt < 2; ++rt)
            aw[kt][rt] = *reinterpret_cast<const short8*>(
                &w3t[(((kt * 16) + w + rt * 8) * 64 + l) * 8]);

    float s1v[2][4], t1v[2][4];
    if (MODE == 2) {
        #pragma unroll
        for (int rt = 0; rt < 2; ++rt)
            #pragma unroll
            for (int j = 0; j < 4; ++j) {
                int col = gbase0 + rt * 128 + j;
                s1v[rt][j] = stats[S_S1 + col];
                t1v[rt][j] = stats[S_T1 + col];
            }
    }
    float ls[2][4] = {{0,0,0,0},{0,0,0,0}}, lq[2][4] = {{0,0,0,0},{0,0,0,0}};
    float bsum = 0.f, bssq = 0.f;

    // ---- prologue: prefetch tile0's Q rows (idx->Q chain) and P rows ----
    uint2 qpf[12];
    uint4 ppf = {0u,0u,0u,0u};
    {
        int r0 = blockIdx.x * 96, n0a = blockIdx.x * 8;
        #pragma unroll
        for (int i = 0; i < 12; ++i) {
            int row = i * 8 + w;
            int jr = nbr_idx[r0 + row];
            qpf[i] = *reinterpret_cast<const uint2*>(&Qb[(size_t)jr * 256 + l * 4]);
        }
        if (t < 256) {
            int row = t >> 5, seg = t & 31;
            ppf = *reinterpret_cast<const uint4*>(&Pb[(size_t)(n0a + row) * 256 + seg * 8]);
        }
    }

    for (int tile = blockIdx.x; tile < NTILES_E; tile += GRID_E) {
        const int r0 = tile * 96;
        const int n0a = tile * 8;

        // issue this tile's nbr NT loads (latency hides under barrier+LDS writes)
        u32x4 nra[2], nrb[2];
        #pragma unroll
        for (int i = 0; i < 2; ++i) {
            int o = t + i * 512;
            if (o < 768) {
                int row = o >> 3, seg = o & 7;
                const u32x4* src = reinterpret_cast<const u32x4*>(
                    nbr_fea + (size_t)(r0 + row) * E_FEA + seg * 8);
                nra[i] = __builtin_nontemporal_load(src);
                nrb[i] = __builtin_nontemporal_load(src + 1);
            }
        }

        __syncthreads();   // previous-iteration LDS readers done

        // write prefetched Q/P registers -> LDS
        #pragma unroll
        for (int i = 0; i < 12; ++i) {
            int row = i * 8 + w;
            *reinterpret_cast<uint2*>(&q_lds[row * QPAD2 + l * 4]) = qpf[i];
        }
        if (t < 256) {
            int row = t >> 5, seg = t & 31;
            *reinterpret_cast<uint4*>(&p_lds[row * PPAD2 + seg * 8]) = ppf;
        }
        // convert + write nbr tile
        #pragma unroll
        for (int i = 0; i < 2; ++i) {
            int o = t + i * 512;
            if (o < 768) {
                int row = o >> 3, seg = o & 7;
                u32x4 a = nra[i], b = nrb[i];
                u32x4 pk;
                pk.x = (u32)f2bf_u(a.x) | ((u32)f2bf_u(a.y) << 16);
                pk.y = (u32)f2bf_u(a.z) | ((u32)f2bf_u(a.w) << 16);
                pk.z = (u32)f2bf_u(b.x) | ((u32)f2bf_u(b.y) << 16);
                pk.w = (u32)f2bf_u(b.z) | ((u32)f2bf_u(b.w) << 16);
                *reinterpret_cast<u32x4*>(&e_lds[row * EPAD + seg * 8]) = pk;
            }
        }
        // issue NEXT tile's idx->Q / P prefetch (hidden under MFMA+epilogue)
        {
            int ntile = tile + GRID_E;
            if (ntile < NTILES_E) {
                int nr0 = ntile * 96, nn0 = ntile * 8;
                #pragma unroll
                for (int i = 0; i < 12; ++i) {
                    int row = i * 8 + w;
                    int jr = nbr_idx[nr0 + row];
                    qpf[i] = *reinterpret_cast<const uint2*>(&Qb[(size_t)jr * 256 + l * 4]);
                }
                if (t < 256) {
                    int row = t >> 5, seg = t & 31;
                    ppf = *reinterpret_cast<const uint4*>(&Pb[(size_t)(nn0 + row) * 256 + seg * 8]);
                }
            }
        }
        __syncthreads();

        // ---- MFMA: gated^T tile, acc[rt][ct] ----
        f32x4 acc[2][6];
        #pragma unroll
        for (int rt = 0; rt < 2; ++rt)
            #pragma unroll
            for (int ct = 0; ct < 6; ++ct)
                acc[rt][ct] = (f32x4){0.f,0.f,0.f,0.f};
        #pragma unroll
        for (int kt = 0; kt < 2; ++kt) {
            short8 bf[6];
            #pragma unroll
            for (int ct = 0; ct < 6; ++ct)
                bf[ct] = *reinterpret_cast<const short8*>(
                    &e_lds[(ct * 16 + fr) * EPAD + kt * 32 + fq * 8]);
            #pragma unroll
            for (int rt = 0; rt < 2; ++rt)
                #pragma unroll
                for (int ct = 0; ct < 6; ++ct)
                    acc[rt][ct] = __builtin_amdgcn_mfma_f32_16x16x32_bf16(
                        aw[kt][rt], bf[ct], acc[rt][ct], 0, 0, 0);
        }

        if (MODE == 1) {
            #pragma unroll
            for (int ct = 0; ct < 6; ++ct) {
                int edge = ct * 16 + fr;
                int atom = (edge * 171) >> 11;     // edge/12
                uint2 qv0 = *reinterpret_cast<const uint2*>(&q_lds[edge * QPAD2 + gbase0]);
                uint2 qv1 = *reinterpret_cast<const uint2*>(&q_lds[edge * QPAD2 + gbase0 + 128]);
                uint2 pv0 = *reinterpret_cast<const uint2*>(&p_lds[atom * PPAD2 + gbase0]);
                uint2 pv1 = *reinterpret_cast<const uint2*>(&p_lds[atom * PPAD2 + gbase0 + 128]);
                float g;
                g = acc[0][ct][0] + bflo(qv0.x) + bflo(pv0.x); ls[0][0] += g; lq[0][0] = fmaf(g,g,lq[0][0]);
                g = acc[0][ct][1] + bfhi(qv0.x) + bfhi(pv0.x); ls[0][1] += g; lq[0][1] = fmaf(g,g,lq[0][1]);
                g = acc[0][ct][2] + bflo(qv0.y) + bflo(pv0.y); ls[0][2] += g; lq[0][2] = fmaf(g,g,lq[0][2]);
                g = acc[0][ct][3] + bfhi(qv0.y) + bfhi(pv0.y); ls[0][3] += g; lq[0][3] = fmaf(g,g,lq[0][3]);
                g = acc[1][ct][0] + bflo(qv1.x) + bflo(pv1.x); ls[1][0] += g; lq[1][0] = fmaf(g,g,lq[1][0]);
                g = acc[1][ct][1] + bfhi(qv1.x) + bfhi(pv1.x); ls[1][1] += g; lq[1][1] = fmaf(g,g,lq[1][1]);
                g = acc[1][ct][2] + bflo(qv1.y) + bflo(pv1.y); ls[1][2] += g; lq[1][2] = fmaf(g,g,lq[1][2]);
                g = acc[1][ct][3] + bfhi(qv1.y) + bfhi(pv1.y); ls[1][3] += g; lq[1][3] = fmaf(g,g,lq[1][3]);
            }
        } else {
            float ar[6][4];
            #pragma unroll
            for (int ct = 0; ct < 6; ++ct) {
                int edge = ct * 16 + fr;
                int atom = (edge * 171) >> 11;
                uint2 qv0 = *reinterpret_cast<const uint2*>(&q_lds[edge * QPAD2 + gbase0]);
                uint2 qv1 = *reinterpret_cast<const uint2*>(&q_lds[edge * QPAD2 + gbase0 + 128]);
                uint2 pv0 = *reinterpret_cast<const uint2*>(&p_lds[atom * PPAD2 + gbase0]);
                uint2 pv1 = *reinterpret_cast<const uint2*>(&p_lds[atom * PPAD2 + gbase0 + 128]);
                float gf, gc;
                gf = acc[0][ct][0] + bflo(qv0.x) + bflo(pv0.x);
                gc = acc[1][ct][0] + bflo(qv1.x) + bflo(pv1.x);
                ar[ct][0] = sigmoid_f(fmaf(gf, s1v[0][0], t1v[0][0])) * softplus_f(fmaf(gc, s1v[1][0], t1v[1][0]));
                gf = acc[0][ct][1] + bfhi(qv0.x) + bfhi(pv0.x);
                gc = acc[1][ct][1] + bfhi(qv1.x) + bfhi(pv1.x);
                ar[ct][1] = sigmoid_f(fmaf(gf, s1v[0][1], t1v[0][1])) * softplus_f(fmaf(gc, s1v[1][1], t1v[1][1]));
                gf = acc[0][ct][2] + bflo(qv0.y) + bflo(pv0.y);
                gc = acc[1][ct][2] + bflo(qv1.y) + bflo(pv1.y);
                ar[ct][2] = sigmoid_f(fmaf(gf, s1v[0][2], t1v[0][2])) * softplus_f(fmaf(gc, s1v[1][2], t1v[1][2]));
                gf = acc[0][ct][3] + bfhi(qv0.y) + bfhi(pv0.y);
                gc = acc[1][ct][3] + bfhi(qv1.y) + bfhi(pv1.y);
                ar[ct][3] = sigmoid_f(fmaf(gf, s1v[0][3], t1v[0][3])) * softplus_f(fmaf(gc, s1v[1][3], t1v[1][3]));
            }
            __syncthreads();   // everyone done reading q_lds; act overlays it
            #pragma unroll
            for (int ct = 0; ct < 6; ++ct) {
                int edge = ct * 16 + fr;
                float4 f4 = make_float4(ar[ct][0], ar[ct][1], ar[ct][2], ar[ct][3]);
                *reinterpret_cast<float4*>(&act[edge * ACT2 + gbase0]) = f4;
            }
            __syncthreads();
            // m-sum -> nbr_sumed -> out; bn2 stats
            #pragma unroll
            for (int i = 0; i < 2; ++i) {
                int o = i * 512 + t;
                int a = o >> 7;            // atom 0..7
                int c = t & 127;
                float S = 0.f;
                #pragma unroll
                for (int mm = 0; mm < 12; ++mm)
                    S += act[(a * 12 + mm) * ACT2 + c];
                out_ns[(size_t)(n0a + a) * A_FEA + c] = S;
                bsum += S;
                bssq = fmaf(S, S, bssq);
            }
        }
    }

    if (MODE == 1) {
        #pragma unroll
        for (int rt = 0; rt < 2; ++rt)
            #pragma unroll
            for (int j = 0; j < 4; ++j) {
                float s = ls[rt][j], q = lq[rt][j];
                s += __shfl_xor(s, 1, 64);  s += __shfl_xor(s, 2, 64);
                s += __shfl_xor(s, 4, 64);  s += __shfl_xor(s, 8, 64);
                q += __shfl_xor(q, 1, 64);  q += __shfl_xor(q, 2, 64);
                q += __shfl_xor(q, 4, 64);  q += __shfl_xor(q, 8, 64);
                if (fr == 0) {
                    int col = gbase0 + rt * 128 + j;
                    atomicAdd(&stats[S_BN1SUM + col], s);
                    atomicAdd(&stats[S_BN1SSQ + col], q);
                }
            }
    } else {
        __syncthreads();
        if (t >= 128) {
            red[(t - 128) * 2]     = bsum;
            red[(t - 128) * 2 + 1] = bssq;
        }
        __syncthreads();
        if (t < 128) {
            bsum += red[t * 2]     + red[(128 + t) * 2]     + red[(256 + t) * 2];
            bssq += red[t * 2 + 1] + red[(128 + t) * 2 + 1] + red[(256 + t) * 2 + 1];
            atomicAdd(&stats[S_BN2SUM + t], bsum);
            atomicAdd(&stats[S_BN2SSQ + t], bssq);
        }
    }
}

// Skip GEMM + bn2 affine + softplus (in place on out).
#define BM5 64
__launch_bounds__(256, 2)
__global__ void skip_kernel(const float* __restrict__ atom_in,
                            const u16* __restrict__ wsf,
                            const float* __restrict__ b_skip,
                            const float* __restrict__ stats,
                            float* __restrict__ out) {
    __shared__ u16 a5[BM5 * 136];
    const int t = threadIdx.x;
    const int w = t >> 6, l = t & 63, fr = l & 15, fq = l >> 4;
    const int n0 = blockIdx.x * BM5;

    #pragma unroll
    for (int it = 0; it < 4; ++it) {
        int c = t + it * 256;
        int row = c >> 4, seg = c & 15;
        int n = n0 + row;
        uint4 pk = {0u, 0u, 0u, 0u};
        if (n < N_ATOM) {
            const float* src = atom_in + (size_t)n * A_FEA + seg * 8;
            float4 x0 = *reinterpret_cast<const float4*>(src);
            float4 x1 = *reinterpret_cast<const float4*>(src + 4);
            pk.x = (u32)f2bf(x0.x) | ((u32)f2bf(x0.y) << 16);
            pk.y = (u32)f2bf(x0.z) | ((u32)f2bf(x0.w) << 16);
            pk.z = (u32)f2bf(x1.x) | ((u32)f2bf(x1.y) << 16);
            pk.w = (u32)f2bf(x1.z) | ((u32)f2bf(x1.w) << 16);
        }
        *reinterpret_cast<uint4*>(&a5[row * 136 + seg * 8]) = pk;
    }
    __syncthreads();

    f32x4 acc[4][2];
    #pragma unroll
    for (int rt = 0; rt < 4; ++rt) {
        acc[rt][0] = (f32x4){0.f,0.f,0.f,0.f};
        acc[rt][1] = (f32x4){0.f,0.f,0.f,0.f};
    }
    for (int kt = 0; kt < 4; ++kt) {
        short8 af[4], bf[2];
        #pragma unroll
        for (int rt = 0; rt < 4; ++rt)
            af[rt] = *reinterpret_cast<const short8*>(
                &a5[(rt * 16 + fr) * 136 + kt * 32 + fq * 8]);
        #pragma unroll
        for (int p = 0; p < 2; ++p)
            bf[p] = *reinterpret_cast<const short8*>(
                &wsf[((kt * 8 + 2 * w + p) * 64 + l) * 8]);
        #pragma unroll
        for (int rt = 0; rt < 4; ++rt)
            #pragma unroll
            for (int p = 0; p < 2; ++p)
                acc[rt][p] = __builtin_amdgcn_mfma_f32_16x16x32_bf16(
                    af[rt], bf[p], acc[rt][p], 0, 0, 0);
    }

    #pragma unroll
    for (int p = 0; p < 2; ++p) {
        int col = w * 32 + p * 16 + fr;
        float bs = b_skip[col];
        float s2 = stats[S_S2 + col];
        float t2 = stats[S_T2 + col];
        #pragma unroll
        for (int rt = 0; rt < 4; ++rt)
            #pragma unroll
            for (int j = 0; j < 4; ++j) {
                int n = n0 + rt * 16 + fq * 4 + j;
                if (n < N_ATOM) {
                    size_t o = (size_t)n * A_FEA + col;
                    float S = out[o];
                    out[o] = softplus_f(acc[rt][p][j] + bs + fmaf(S, s2, t2));
                }
            }
    }
}

// =====================================================================
// SLOW fallback path (round-2 validated code, unchanged)
// =====================================================================
#define BM 96
#define NTILES (ROWS/BM)
#define GRID_P 2500
#define TPB 256
#define APAD 328
#define ACTPAD 132

__global__ void prep_pack_slow(const float* __restrict__ Wfull,
                               const float* __restrict__ Wskip,
                               u16* __restrict__ wf, u16* __restrict__ wsf) {
    int tid = blockIdx.x * blockDim.x + threadIdx.x;
    if (tid < 10240) {
        int l = tid & 63;
        int ct = (tid >> 6) & 15;
        int kt = tid >> 10;
        int fr = l & 15, fq = l >> 4;
        int col = ct * 16 + fr;
        int k0 = kt * 32 + fq * 8;
        u16 tmp[8];
        #pragma unroll
        for (int i = 0; i < 8; ++i) tmp[i] = f2bf(Wfull[(k0 + i) * GDIM + col]);
        uint4 pk;
        pk.x = (u32)tmp[0] | ((u32)tmp[1] << 16);
        pk.y = (u32)tmp[2] | ((u32)tmp[3] << 16);
        pk.z = (u32)tmp[4] | ((u32)tmp[5] << 16);
        pk.w = (u32)tmp[6] | ((u32)tmp[7] << 16);
        *reinterpret_cast<uint4*>(&wf[tid * 8]) = pk;
    } else if (tid < 12288) {
        int t2 = tid - 10240;
        int l = t2 & 63;
        int ct = (t2 >> 6) & 7;
        int kt = t2 >> 9;
        int fr = l & 15, fq = l >> 4;
        int col = ct * 16 + fr;
        int k0 = kt * 32 + fq * 8;
        u16 tmp[8];
        #pragma unroll
        for (int i = 0; i < 8; ++i) tmp[i] = f2bf(Wskip[(k0 + i) * A_FEA + col]);
        uint4 pk;
        pk.x = (u32)tmp[0] | ((u32)tmp[1] << 16);
        pk.y = (u32)tmp[2] | ((u32)tmp[3] << 16);
        pk.z = (u32)tmp[4] | ((u32)tmp[5] << 16);
        pk.w = (u32)tmp[6] | ((u32)tmp[7] << 16);
        *reinterpret_cast<uint4*>(&wsf[t2 * 8]) = pk;
    }
}

template<int PASS>
__launch_bounds__(TPB, 2)
__global__ void pass_kernel(const float* __restrict__ atom_in,
                            const float* __restrict__ nbr_fea,
                            const int* __restrict__ nbr_idx,
                            const u16* __restrict__ wf,
                            float* __restrict__ stats,
                            float* __restrict__ out_ns) {
    __shared__ union {
        u16 a[BM * APAD];
        float act[BM * ACTPAD];
    } sh;

    const int t = threadIdx.x;
    const int w = t >> 6, l = t & 63, fr = l & 15, fq = l >> 4;
    const int ct0 = 2 * w;

    int colp[4];
    colp[0] = ct0 * 16 + fr;
    colp[1] = colp[0] + 16;
    colp[2] = colp[0] + 128;
    colp[3] = colp[1] + 128;

    float s1v[4], t1v[4];
    if (PASS == 2) {
        #pragma unroll
        for (int p = 0; p < 4; ++p) {
            s1v[p] = stats[S_S1 + colp[p]];
            t1v[p] = stats[S_T1 + colp[p]];
        }
    }
    float ls[4] = {0.f,0.f,0.f,0.f}, lq[4] = {0.f,0.f,0.f,0.f};
    float bsum = 0.f, bssq = 0.f;

    for (int tile = blockIdx.x; tile < NTILES; tile += GRID_P) {
        const int n0 = tile * 8;

        __syncthreads();
        for (int it = 0; it < 15; ++it) {
            int c = t + it * TPB;
            int row = c / 40;
            int seg = c - row * 40;
            int an = row / 12;
            int m  = row - an * 12;
            int na = n0 + an;
            const float* src;
            if (seg < 16) {
                src = atom_in + (size_t)na * A_FEA + seg * 8;
            } else if (seg < 32) {
                int j = nbr_idx[na * M_NBR + m];
                src = atom_in + (size_t)j * A_FEA + (seg - 16) * 8;
            } else {
                src = nbr_fea + ((size_t)na * M_NBR + m) * E_FEA + (seg - 32) * 8;
            }
            float4 x0 = *reinterpret_cast<const float4*>(src);
            float4 x1 = *reinterpret_cast<const float4*>(src + 4);
            uint4 pk;
            pk.x = (u32)f2bf(x0.x) | ((u32)f2bf(x0.y) << 16);
            pk.y = (u32)f2bf(x0.z) | ((u32)f2bf(x0.w) << 16);
            pk.z = (u32)f2bf(x1.x) | ((u32)f2bf(x1.y) << 16);
            pk.w = (u32)f2bf(x1.z) | ((u32)f2bf(x1.w) << 16);
            *reinterpret_cast<uint4*>(&sh.a[row * APAD + seg * 8]) = pk;
        }
        __syncthreads();

        f32x4 acc[6][4];
        #pragma unroll
        for (int rt = 0; rt < 6; ++rt)
            #pragma unroll
            for (int p = 0; p < 4; ++p)
                acc[rt][p] = (f32x4){0.f,0.f,0.f,0.f};

        for (int kt = 0; kt < 10; ++kt) {
            short8 af[6], bf[4];
            #pragma unroll
            for (int rt = 0; rt < 6; ++rt)
                af[rt] = *reinterpret_cast<const short8*>(
                    &sh.a[(rt * 16 + fr) * APAD + kt * 32 + fq * 8]);
            #pragma unroll
            for (int p = 0; p < 4; ++p) {
                int ct = (p < 2) ? (ct0 + p) : (ct0 + 8 + (p - 2));
                bf[p] = *reinterpret_cast<const short8*>(
                    &wf[((kt * 16 + ct) * 64 + l) * 8]);
            }
            #pragma unroll
            for (int rt = 0; rt < 6; ++rt)
                #pragma unroll
                for (int p = 0; p < 4; ++p)
                    acc[rt][p] = __builtin_amdgcn_mfma_f32_16x16x32_bf16(
                        af[rt], bf[p], acc[rt][p], 0, 0, 0);
        }

        if (PASS == 1) {
            #pragma unroll
            for (int p = 0; p < 4; ++p)
                #pragma unroll
                for (int rt = 0; rt < 6; ++rt)
                    #pragma unroll
                    for (int j = 0; j < 4; ++j) {
                        float v = acc[rt][p][j];
                        ls[p] += v;
                        lq[p] = fmaf(v, v, lq[p]);
                    }
        } else {
            __syncthreads();
            #pragma unroll
            for (int rt = 0; rt < 6; ++rt)
                #pragma unroll
                for (int p = 0; p < 2; ++p)
                    #pragma unroll
                    for (int j = 0; j < 4; ++j) {
                        float gf = fmaf(acc[rt][p][j],     s1v[p],     t1v[p]);
                        float gc = fmaf(acc[rt][2 + p][j], s1v[2 + p], t1v[2 + p]);
                        float a = sigmoid_f(gf) * softplus_f(gc);
                        int row = rt * 16 + fq * 4 + j;
                        int colact = ct0 * 16 + p * 16 + fr;
                        sh.act[row * ACTPAD + colact] = a;
                    }
            __syncthreads();
            #pragma unroll
            for (int i = 0; i < 4; ++i) {
                int o = i * TPB + t;
                int a = o >> 7;
                int c = o & 127;
                float S = 0.f;
                #pragma unroll
                for (int mm = 0; mm < 12; ++mm)
                    S += sh.act[(a * 12 + mm) * ACTPAD + c];
                out_ns[(size_t)(n0 + a) * A_FEA + c] = S;
                bsum += S;
                bssq = fmaf(S, S, bssq);
            }
        }
    }

    if (PASS == 1) {
        #pragma unroll
        for (int p = 0; p < 4; ++p) {
            float s = ls[p], q = lq[p];
            s += __shfl_xor(s, 16, 64);
            s += __shfl_xor(s, 32, 64);
            q += __shfl_xor(q, 16, 64);
            q += __shfl_xor(q, 32, 64);
            if (fq == 0) {
                atomicAdd(&stats[S_BN1SUM + colp[p]], s);
                atomicAdd(&stats[S_BN1SSQ + colp[p]], q);
            }
        }
    } else {
        __syncthreads();
        if (t >= 128) {
            sh.act[(t - 128) * 2]     = bsum;
            sh.act[(t - 128) * 2 + 1] = bssq;
        }
        __syncthreads();
        if (t < 128) {
            bsum += sh.act[t * 2];
            bssq += sh.act[t * 2 + 1];
            atomicAdd(&stats[S_BN2SUM + t], bsum);
            atomicAdd(&stats[S_BN2SSQ + t], bssq);
        }
    }
}

// =====================================================================
extern "C" void kernel_launch(void* const* d_in, const int* in_sizes, int n_in,
                              void* d_out, int out_size, void* d_ws, size_t ws_size,
                              hipStream_t stream) {
    (void)in_sizes; (void)n_in; (void)out_size;
    const float* atom_in = (const float*)d_in[0];
    const float* nbr_fea = (const float*)d_in[1];
    const int*   nbr_idx = (const int*)d_in[2];
    const float* Wfull   = (const float*)d_in[3];
    // d_in[4] = b_full: cancels exactly under batchnorm1 -> unused
    const float* g1      = (const float*)d_in[5];
    const float* b1      = (const float*)d_in[6];
    const float* g2      = (const float*)d_in[7];
    const float* b2      = (const float*)d_in[8];
    const float* Wsk     = (const float*)d_in[9];
    const float* bsk     = (const float*)d_in[10];
    float* out = (float*)d_out;

    float* stats = (float*)((char*)d_ws + STATS_OFF);
    u16* wskf = (u16*)((char*)d_ws + WSK_OFF);

    if (ws_size >= NEED_FAST3) {
        u16* wpq = (u16*)d_ws;
        u16* w3t = (u16*)((char*)d_ws + W3T_OFF);
        u16* Pb  = (u16*)((char*)d_ws + P_OFF);
        u16* Qb  = (u16*)((char*)d_ws + Q_OFF);

        zero_stats<<<1, 256, 0, stream>>>(stats);
        prep_pack2<<<48, 256, 0, stream>>>(Wfull, Wsk, wpq, w3t, wskf);
        pq_kernel<<<(N_ATOM + 63) / 64, 256, 0, stream>>>(atom_in, wpq, Pb, Qb);
        estage4<1><<<GRID_E, 512, 0, stream>>>(nbr_fea, nbr_idx, w3t, Pb, Qb, stats, out);
        finalize1<<<1, 256, 0, stream>>>(g1, b1, stats);
        estage4<2><<<GRID_E, 512, 0, stream>>>(nbr_fea, nbr_idx, w3t, Pb, Qb, stats, out);
        finalize2<<<1, 128, 0, stream>>>(g2, b2, stats);
        skip_kernel<<<(N_ATOM + BM5 - 1) / BM5, 256, 0, stream>>>(atom_in, wskf, bsk, stats, out);
    } else {
        u16* wf = (u16*)d_ws;
        zero_stats<<<1, 256, 0, stream>>>(stats);
        prep_pack_slow<<<48, 256, 0, stream>>>(Wfull, Wsk, wf, wskf);
        pass_kernel<1><<<GRID_P, TPB, 0, stream>>>(atom_in, nbr_fea, nbr_idx, wf, stats, out);
        finalize1<<<1, 256, 0, stream>>>(g1, b1, stats);
        pass_kernel<2><<<GRID_P, TPB, 0, stream>>>(atom_in, nbr_fea, nbr_idx, wf, stats, out);
        finalize2<<<1, 128, 0, stream>>>(g2, b2, stats);
        skip_kernel<<<(N_ATOM + BM5 - 1) / BM5, 256, 0, stream>>>(atom_in, wskf, bsk, stats, out);
    }
}

// Round 8
// 1119.912 us; speedup vs baseline: 1.6097x; 1.6097x over previous
//
#include <hip/hip_runtime.h>
#include <stdint.h>

#define N_ATOM 100000
#define M_NBR 12
#define A_FEA 128
#define E_FEA 64
#define KDIM 320
#define GDIM 256
#define ROWS (N_ATOM*M_NBR)
#define BN_EPS 1e-5f

typedef unsigned short u16;
typedef unsigned int u32;
typedef __attribute__((ext_vector_type(8))) short short8;
typedef __attribute__((ext_vector_type(4))) float f32x4;

// ---- stats slot indices (floats) ----
#define S_BN1SUM 0
#define S_BN1SSQ 256
#define S_S1 512
#define S_T1 768
#define S_BN2SUM 1024
#define S_BN2SSQ 1152
#define S_S2 1280
#define S_T2 1408
#define STATS_F32 1536

// ---- workspace layout ----
#define WPQ_OFF 0
#define W3T_OFF 131072
#define WSK_OFF 163840
#define STATS_OFF 196608
#define P_OFF 202752
#define PQ_BYTES ((size_t)N_ATOM*256*2)            // 51,200,000
#define Q_OFF (P_OFF + PQ_BYTES)
#define NEED_FAST3 (P_OFF + 2*PQ_BYTES)            // ~102.6 MB

__device__ __forceinline__ u16 f2bf(float x) {
    union { float f; u32 u; } v; v.f = x;
    u32 r = v.u + 0x7FFFu + ((v.u >> 16) & 1u);
    return (u16)(r >> 16);
}
__device__ __forceinline__ float bflo(u32 x) { return __uint_as_float(x << 16); }
__device__ __forceinline__ float bfhi(u32 x) { return __uint_as_float(x & 0xFFFF0000u); }
__device__ __forceinline__ float softplus_f(float x) {
    return fmaxf(x, 0.f) + __logf(1.f + __expf(-fabsf(x)));
}
__device__ __forceinline__ float sigmoid_f(float x) {
    return 1.f / (1.f + __expf(-x));
}

// Zero bn accumulators every launch (plain kernel -> always a graph node).
__global__ void zero_stats(float* __restrict__ stats) {
    int t = threadIdx.x;              // 256
    stats[t] = 0.f;
    stats[256 + t] = 0.f;
    stats[1024 + t] = 0.f;
}

__global__ void finalize1(const float* __restrict__ g1, const float* __restrict__ b1,
                          float* __restrict__ stats) {
    int c = threadIdx.x;  // 256
    const float inv_cnt = 1.f / (float)ROWS;
    float mean = stats[S_BN1SUM + c] * inv_cnt;
    float var  = stats[S_BN1SSQ + c] * inv_cnt - mean * mean;
    float iv = rsqrtf(var + BN_EPS);
    float s = g1[c] * iv;
    stats[S_S1 + c] = s;
    stats[S_T1 + c] = fmaf(-mean, s, b1[c]);
}

__global__ void finalize2(const float* __restrict__ g2, const float* __restrict__ b2,
                          float* __restrict__ stats) {
    int c = threadIdx.x;  // 128
    const float inv_cnt = 1.f / (float)N_ATOM;
    float mean = stats[S_BN2SUM + c] * inv_cnt;
    float var  = stats[S_BN2SSQ + c] * inv_cnt - mean * mean;
    float iv = rsqrtf(var + BN_EPS);
    float s = g2[c] * iv;
    stats[S_S2 + c] = s;
    stats[S_T2 + c] = fmaf(-mean, s, b2[c]);
}

// Pack Wpq (B for P/Q GEMM: 128 x 512), W3T (A-frags of W3^T: 256 x 64),
// Wsk (128 x 128) into MFMA fragment order.
__global__ void prep_pack2(const float* __restrict__ Wfull,
                           const float* __restrict__ Wskip,
                           u16* __restrict__ wpq, u16* __restrict__ w3t,
                           u16* __restrict__ wsk) {
    int tid = blockIdx.x * blockDim.x + threadIdx.x;
    int l = tid & 63, fr = l & 15, fq = l >> 4;
    if (tid < 8192) {
        int ct = (tid >> 6) & 31;
        int kt = tid >> 11;                 // 0..3
        int c = ct * 16 + fr;               // 0..511
        int k0 = kt * 32 + fq * 8;          // 0..127
        u16 tmp[8];
        #pragma unroll
        for (int i = 0; i < 8; ++i) {
            int kk = k0 + i;
            float v = (c < 256) ? Wfull[kk * GDIM + c]
                                : Wfull[(128 + kk) * GDIM + (c - 256)];
            tmp[i] = f2bf(v);
        }
        uint4 pk;
        pk.x = (u32)tmp[0] | ((u32)tmp[1] << 16);
        pk.y = (u32)tmp[2] | ((u32)tmp[3] << 16);
        pk.z = (u32)tmp[4] | ((u32)tmp[5] << 16);
        pk.w = (u32)tmp[6] | ((u32)tmp[7] << 16);
        *reinterpret_cast<uint4*>(&wpq[tid * 8]) = pk;
    } else if (tid < 10240) {
        // W3T A-frag: frag=(kt*16+rt16), elem i -> Wfull[256+kt*32+fq*8+i][rt16*16+fr]
        int t2 = tid - 8192;               // 0..2047
        int frag = t2 >> 6;                // 0..31
        int rt16 = frag & 15, kt = frag >> 4;
        int gcol = rt16 * 16 + fr;
        int k0 = kt * 32 + fq * 8;
        u16 tmp[8];
        #pragma unroll
        for (int i = 0; i < 8; ++i) tmp[i] = f2bf(Wfull[(256 + k0 + i) * GDIM + gcol]);
        uint4 pk;
        pk.x = (u32)tmp[0] | ((u32)tmp[1] << 16);
        pk.y = (u32)tmp[2] | ((u32)tmp[3] << 16);
        pk.z = (u32)tmp[4] | ((u32)tmp[5] << 16);
        pk.w = (u32)tmp[6] | ((u32)tmp[7] << 16);
        *reinterpret_cast<uint4*>(&w3t[t2 * 8]) = pk;
    } else if (tid < 12288) {
        int t3 = tid - 10240;
        int ct = (t3 >> 6) & 7;
        int kt = t3 >> 9;                   // 0..3
        int c = ct * 16 + fr;
        int k0 = kt * 32 + fq * 8;
        u16 tmp[8];
        #pragma unroll
        for (int i = 0; i < 8; ++i) tmp[i] = f2bf(Wskip[(k0 + i) * A_FEA + c]);
        uint4 pk;
        pk.x = (u32)tmp[0] | ((u32)tmp[1] << 16);
        pk.y = (u32)tmp[2] | ((u32)tmp[3] << 16);
        pk.z = (u32)tmp[4] | ((u32)tmp[5] << 16);
        pk.w = (u32)tmp[6] | ((u32)tmp[7] << 16);
        *reinterpret_cast<uint4*>(&wsk[t3 * 8]) = pk;
    }
}

// P[n] = atom_in[n] @ Wfull[0:128];  Q[n] = atom_in[n] @ Wfull[128:256]
__launch_bounds__(256)
__global__ void pq_kernel(const float* __restrict__ atom_in,
                          const u16* __restrict__ wpq,
                          u16* __restrict__ Pb, u16* __restrict__ Qb) {
    __shared__ u16 al[64 * 130];
    const int t = threadIdx.x;
    const int w = t >> 6, l = t & 63, fr = l & 15, fq = l >> 4;
    const int n0 = blockIdx.x * 64;

    #pragma unroll
    for (int it = 0; it < 4; ++it) {
        int c = t + it * 256;         // 0..1023
        int row = c >> 4, seg = c & 15;
        int n = n0 + row;
        uint4 pk = {0u, 0u, 0u, 0u};
        if (n < N_ATOM) {
            const float* src = atom_in + (size_t)n * A_FEA + seg * 8;
            float4 x0 = *reinterpret_cast<const float4*>(src);
            float4 x1 = *reinterpret_cast<const float4*>(src + 4);
            pk.x = (u32)f2bf(x0.x) | ((u32)f2bf(x0.y) << 16);
            pk.y = (u32)f2bf(x0.z) | ((u32)f2bf(x0.w) << 16);
            pk.z = (u32)f2bf(x1.x) | ((u32)f2bf(x1.y) << 16);
            pk.w = (u32)f2bf(x1.z) | ((u32)f2bf(x1.w) << 16);
        }
        *reinterpret_cast<uint4*>(&al[row * 130 + seg * 8]) = pk;
    }
    __syncthreads();

    f32x4 acc[4][8];
    #pragma unroll
    for (int rt = 0; rt < 4; ++rt)
        #pragma unroll
        for (int p = 0; p < 8; ++p)
            acc[rt][p] = (f32x4){0.f,0.f,0.f,0.f};

    for (int kt = 0; kt < 4; ++kt) {
        short8 af[4], bf[8];
        #pragma unroll
        for (int rt = 0; rt < 4; ++rt)
            af[rt] = *reinterpret_cast<const short8*>(
                &al[(rt * 16 + fr) * 130 + kt * 32 + fq * 8]);
        #pragma unroll
        for (int p = 0; p < 8; ++p)
            bf[p] = *reinterpret_cast<const short8*>(
                &wpq[((kt * 32 + w * 8 + p) * 64 + l) * 8]);
        #pragma unroll
        for (int rt = 0; rt < 4; ++rt)
            #pragma unroll
            for (int p = 0; p < 8; ++p)
                acc[rt][p] = __builtin_amdgcn_mfma_f32_16x16x32_bf16(
                    af[rt], bf[p], acc[rt][p], 0, 0, 0);
    }

    #pragma unroll
    for (int p = 0; p < 8; ++p) {
        int col = w * 128 + p * 16 + fr;            // 0..511
        u16* dst = (col < 256) ? Pb : Qb;
        int cc = (col < 256) ? col : (col - 256);
        #pragma unroll
        for (int rt = 0; rt < 4; ++rt)
            #pragma unroll
            for (int j = 0; j < 4; ++j) {
                int n = n0 + rt * 16 + fq * 4 + j;
                if (n < N_ATOM) dst[(size_t)n * 256 + cc] = f2bf(acc[rt][p][j]);
            }
    }
}

// =====================================================================
// Edge kernel v5 = R6's transposed-MFMA structure + R4's inline f32->bf16
// staging with plain cached loads. No nbf buffer, no NT, no reg prefetch.
// tile = 96 edges (8 atoms x 12), 512 threads (8 waves).
// gated^T = W3^T @ nbr^T; epilogue reads P/Q as vectorized LDS uint2.
// MODE 1: bn1 sum/ssq. MODE 2: act -> m-sum -> out, bn2 stats.
// =====================================================================
#define NTILES_E (ROWS/96)     // 12500
#define GRID_E 2500
#define EPAD 66                // u16 stride of nbr tile rows
#define PPAD2 264              // u16 stride of P rows
#define QPAD2 268              // u16 stride of Q rows
#define ACT2 132               // f32 stride of act rows
#define E_SH (96*EPAD*2)                // 12672
#define P_SH0 E_SH                      // p at +12672 (4224 B)
#define Q_SH0 (E_SH + 8*PPAD2*2)        // q at +16896 (51456 B)
#define SH_TOT (Q_SH0 + 96*QPAD2*2)     // 68352; act overlay 96*132*4=50688 <= 51456

template<int MODE>
__launch_bounds__(512, 4)
__global__ void estage5(const float* __restrict__ nbr_fea,
                        const int* __restrict__ nbr_idx,
                        const u16* __restrict__ w3t,
                        const u16* __restrict__ Pb,
                        const u16* __restrict__ Qb,
                        float* __restrict__ stats,
                        float* __restrict__ out_ns) {
    __shared__ __align__(16) unsigned char shraw[SH_TOT];
    u16* e_lds = (u16*)shraw;
    u16* p_lds = (u16*)(shraw + P_SH0);
    u16* q_lds = (u16*)(shraw + Q_SH0);
    float* act = (float*)(shraw + Q_SH0);
    float* red = (float*)shraw;

    const int t = threadIdx.x;
    const int w = t >> 6, l = t & 63, fr = l & 15, fq = l >> 4;
    const int gbase0 = w * 16 + fq * 4;        // filter col base (rt=0); core = +128

    // Tile-invariant W3^T A-fragments.
    short8 aw[2][2];
    #pragma unroll
    for (int kt = 0; kt < 2; ++kt)
        #pragma unroll
        for (int rt = 0; rt < 2; ++rt)
            aw[kt][rt] = *reinterpret_cast<const short8*>(
                &w3t[(((kt * 16) + w + rt * 8) * 64 + l) * 8]);

    float s1v[2][4], t1v[2][4];
    if (MODE == 2) {
        #pragma unroll
        for (int rt = 0; rt < 2; ++rt)
            #pragma unroll
            for (int j = 0; j < 4; ++j) {
                int col = gbase0 + rt * 128 + j;
                s1v[rt][j] = stats[S_S1 + col];
                t1v[rt][j] = stats[S_T1 + col];
            }
    }
    float ls[2][4] = {{0,0,0,0},{0,0,0,0}}, lq[2][4] = {{0,0,0,0},{0,0,0,0}};
    float bsum = 0.f, bssq = 0.f;

    for (int tile = blockIdx.x; tile < NTILES_E; tile += GRID_E) {
        const int r0 = tile * 96;
        const int n0a = tile * 8;

        __syncthreads();   // protect LDS from previous-iteration readers

        // ---- stage nbr tile: 96 x 64 f32 -> bf16 (plain cached loads) ----
        #pragma unroll
        for (int i = 0; i < 2; ++i) {
            int o = t + i * 512;
            if (o < 768) {
                int row = o >> 3, seg = o & 7;
                const float* src = nbr_fea + (size_t)(r0 + row) * E_FEA + seg * 8;
                float4 x0 = *reinterpret_cast<const float4*>(src);
                float4 x1 = *reinterpret_cast<const float4*>(src + 4);
                uint4 pk;
                pk.x = (u32)f2bf(x0.x) | ((u32)f2bf(x0.y) << 16);
                pk.y = (u32)f2bf(x0.z) | ((u32)f2bf(x0.w) << 16);
                pk.z = (u32)f2bf(x1.x) | ((u32)f2bf(x1.y) << 16);
                pk.w = (u32)f2bf(x1.z) | ((u32)f2bf(x1.w) << 16);
                *reinterpret_cast<uint4*>(&e_lds[row * EPAD + seg * 8]) = pk;
            }
        }
        // ---- stage P rows: 8 x 256 bf16 ----
        if (t < 256) {
            int row = t >> 5, seg = t & 31;
            *reinterpret_cast<uint4*>(&p_lds[row * PPAD2 + seg * 8]) =
                *reinterpret_cast<const uint4*>(&Pb[(size_t)(n0a + row) * 256 + seg * 8]);
        }
        // ---- stage Q[idx]: 96 rows, one row per wave-iter, 512B bursts ----
        #pragma unroll
        for (int i = 0; i < 12; ++i) {
            int row = i * 8 + w;
            int jr = nbr_idx[r0 + row];
            *reinterpret_cast<uint2*>(&q_lds[row * QPAD2 + l * 4]) =
                *reinterpret_cast<const uint2*>(&Qb[(size_t)jr * 256 + l * 4]);
        }
        __syncthreads();

        // ---- MFMA: gated^T tile, acc[rt][ct] ----
        f32x4 acc[2][6];
        #pragma unroll
        for (int rt = 0; rt < 2; ++rt)
            #pragma unroll
            for (int ct = 0; ct < 6; ++ct)
                acc[rt][ct] = (f32x4){0.f,0.f,0.f,0.f};
        #pragma unroll
        for (int kt = 0; kt < 2; ++kt) {
            short8 bf[6];
            #pragma unroll
            for (int ct = 0; ct < 6; ++ct)
                bf[ct] = *reinterpret_cast<const short8*>(
                    &e_lds[(ct * 16 + fr) * EPAD + kt * 32 + fq * 8]);
            #pragma unroll
            for (int rt = 0; rt < 2; ++rt)
                #pragma unroll
                for (int ct = 0; ct < 6; ++ct)
                    acc[rt][ct] = __builtin_amdgcn_mfma_f32_16x16x32_bf16(
                        aw[kt][rt], bf[ct], acc[rt][ct], 0, 0, 0);
        }

        if (MODE == 1) {
            #pragma unroll
            for (int ct = 0; ct < 6; ++ct) {
                int edge = ct * 16 + fr;
                int atom = (edge * 171) >> 11;     // edge/12
                uint2 qv0 = *reinterpret_cast<const uint2*>(&q_lds[edge * QPAD2 + gbase0]);
                uint2 qv1 = *reinterpret_cast<const uint2*>(&q_lds[edge * QPAD2 + gbase0 + 128]);
                uint2 pv0 = *reinterpret_cast<const uint2*>(&p_lds[atom * PPAD2 + gbase0]);
                uint2 pv1 = *reinterpret_cast<const uint2*>(&p_lds[atom * PPAD2 + gbase0 + 128]);
                float g;
                g = acc[0][ct][0] + bflo(qv0.x) + bflo(pv0.x); ls[0][0] += g; lq[0][0] = fmaf(g,g,lq[0][0]);
                g = acc[0][ct][1] + bfhi(qv0.x) + bfhi(pv0.x); ls[0][1] += g; lq[0][1] = fmaf(g,g,lq[0][1]);
                g = acc[0][ct][2] + bflo(qv0.y) + bflo(pv0.y); ls[0][2] += g; lq[0][2] = fmaf(g,g,lq[0][2]);
                g = acc[0][ct][3] + bfhi(qv0.y) + bfhi(pv0.y); ls[0][3] += g; lq[0][3] = fmaf(g,g,lq[0][3]);
                g = acc[1][ct][0] + bflo(qv1.x) + bflo(pv1.x); ls[1][0] += g; lq[1][0] = fmaf(g,g,lq[1][0]);
                g = acc[1][ct][1] + bfhi(qv1.x) + bfhi(pv1.x); ls[1][1] += g; lq[1][1] = fmaf(g,g,lq[1][1]);
                g = acc[1][ct][2] + bflo(qv1.y) + bflo(pv1.y); ls[1][2] += g; lq[1][2] = fmaf(g,g,lq[1][2]);
                g = acc[1][ct][3] + bfhi(qv1.y) + bfhi(pv1.y); ls[1][3] += g; lq[1][3] = fmaf(g,g,lq[1][3]);
            }
        } else {
            float ar[6][4];
            #pragma unroll
            for (int ct = 0; ct < 6; ++ct) {
                int edge = ct * 16 + fr;
                int atom = (edge * 171) >> 11;
                uint2 qv0 = *reinterpret_cast<const uint2*>(&q_lds[edge * QPAD2 + gbase0]);
                uint2 qv1 = *reinterpret_cast<const uint2*>(&q_lds[edge * QPAD2 + gbase0 + 128]);
                uint2 pv0 = *reinterpret_cast<const uint2*>(&p_lds[atom * PPAD2 + gbase0]);
                uint2 pv1 = *reinterpret_cast<const uint2*>(&p_lds[atom * PPAD2 + gbase0 + 128]);
                float gf, gc;
                gf = acc[0][ct][0] + bflo(qv0.x) + bflo(pv0.x);
                gc = acc[1][ct][0] + bflo(qv1.x) + bflo(pv1.x);
                ar[ct][0] = sigmoid_f(fmaf(gf, s1v[0][0], t1v[0][0])) * softplus_f(fmaf(gc, s1v[1][0], t1v[1][0]));
                gf = acc[0][ct][1] + bfhi(qv0.x) + bfhi(pv0.x);
                gc = acc[1][ct][1] + bfhi(qv1.x) + bfhi(pv1.x);
                ar[ct][1] = sigmoid_f(fmaf(gf, s1v[0][1], t1v[0][1])) * softplus_f(fmaf(gc, s1v[1][1], t1v[1][1]));
                gf = acc[0][ct][2] + bflo(qv0.y) + bflo(pv0.y);
                gc = acc[1][ct][2] + bflo(qv1.y) + bflo(pv1.y);
                ar[ct][2] = sigmoid_f(fmaf(gf, s1v[0][2], t1v[0][2])) * softplus_f(fmaf(gc, s1v[1][2], t1v[1][2]));
                gf = acc[0][ct][3] + bfhi(qv0.y) + bfhi(pv0.y);
                gc = acc[1][ct][3] + bfhi(qv1.y) + bfhi(pv1.y);
                ar[ct][3] = sigmoid_f(fmaf(gf, s1v[0][3], t1v[0][3])) * softplus_f(fmaf(gc, s1v[1][3], t1v[1][3]));
            }
            __syncthreads();   // everyone done reading q_lds; act overlays it
            #pragma unroll
            for (int ct = 0; ct < 6; ++ct) {
                int edge = ct * 16 + fr;
                float4 f4 = make_float4(ar[ct][0], ar[ct][1], ar[ct][2], ar[ct][3]);
                *reinterpret_cast<float4*>(&act[edge * ACT2 + gbase0]) = f4;
            }
            __syncthreads();
            // m-sum -> nbr_sumed -> out; bn2 stats
            #pragma unroll
            for (int i = 0; i < 2; ++i) {
                int o = i * 512 + t;
                int a = o >> 7;            // atom 0..7
                int c = t & 127;
                float S = 0.f;
                #pragma unroll
                for (int mm = 0; mm < 12; ++mm)
                    S += act[(a * 12 + mm) * ACT2 + c];
                out_ns[(size_t)(n0a + a) * A_FEA + c] = S;
                bsum += S;
                bssq = fmaf(S, S, bssq);
            }
        }
    }

    if (MODE == 1) {
        #pragma unroll
        for (int rt = 0; rt < 2; ++rt)
            #pragma unroll
            for (int j = 0; j < 4; ++j) {
                float s = ls[rt][j], q = lq[rt][j];
                s += __shfl_xor(s, 1, 64);  s += __shfl_xor(s, 2, 64);
                s += __shfl_xor(s, 4, 64);  s += __shfl_xor(s, 8, 64);
                q += __shfl_xor(q, 1, 64);  q += __shfl_xor(q, 2, 64);
                q += __shfl_xor(q, 4, 64);  q += __shfl_xor(q, 8, 64);
                if (fr == 0) {
                    int col = gbase0 + rt * 128 + j;
                    atomicAdd(&stats[S_BN1SUM + col], s);
                    atomicAdd(&stats[S_BN1SSQ + col], q);
                }
            }
    } else {
        __syncthreads();
        if (t >= 128) {
            red[(t - 128) * 2]     = bsum;
            red[(t - 128) * 2 + 1] = bssq;
        }
        __syncthreads();
        if (t < 128) {
            bsum += red[t * 2]     + red[(128 + t) * 2]     + red[(256 + t) * 2];
            bssq += red[t * 2 + 1] + red[(128 + t) * 2 + 1] + red[(256 + t) * 2 + 1];
            atomicAdd(&stats[S_BN2SUM + t], bsum);
            atomicAdd(&stats[S_BN2SSQ + t], bssq);
        }
    }
}

// Skip GEMM + bn2 affine + softplus (in place on out).
#define BM5 64
__launch_bounds__(256, 2)
__global__ void skip_kernel(const float* __restrict__ atom_in,
                            const u16* __restrict__ wsf,
                            const float* __restrict__ b_skip,
                            const float* __restrict__ stats,
                            float* __restrict__ out) {
    __shared__ u16 a5[BM5 * 136];
    const int t = threadIdx.x;
    const int w = t >> 6, l = t & 63, fr = l & 15, fq = l >> 4;
    const int n0 = blockIdx.x * BM5;

    #pragma unroll
    for (int it = 0; it < 4; ++it) {
        int c = t + it * 256;
        int row = c >> 4, seg = c & 15;
        int n = n0 + row;
        uint4 pk = {0u, 0u, 0u, 0u};
        if (n < N_ATOM) {
            const float* src = atom_in + (size_t)n * A_FEA + seg * 8;
            float4 x0 = *reinterpret_cast<const float4*>(src);
            float4 x1 = *reinterpret_cast<const float4*>(src + 4);
            pk.x = (u32)f2bf(x0.x) | ((u32)f2bf(x0.y) << 16);
            pk.y = (u32)f2bf(x0.z) | ((u32)f2bf(x0.w) << 16);
            pk.z = (u32)f2bf(x1.x) | ((u32)f2bf(x1.y) << 16);
            pk.w = (u32)f2bf(x1.z) | ((u32)f2bf(x1.w) << 16);
        }
        *reinterpret_cast<uint4*>(&a5[row * 136 + seg * 8]) = pk;
    }
    __syncthreads();

    f32x4 acc[4][2];
    #pragma unroll
    for (int rt = 0; rt < 4; ++rt) {
        acc[rt][0] = (f32x4){0.f,0.f,0.f,0.f};
        acc[rt][1] = (f32x4){0.f,0.f,0.f,0.f};
    }
    for (int kt = 0; kt < 4; ++kt) {
        short8 af[4], bf[2];
        #pragma unroll
        for (int rt = 0; rt < 4; ++rt)
            af[rt] = *reinterpret_cast<const short8*>(
                &a5[(rt * 16 + fr) * 136 + kt * 32 + fq * 8]);
        #pragma unroll
        for (int p = 0; p < 2; ++p)
            bf[p] = *reinterpret_cast<const short8*>(
                &wsf[((kt * 8 + 2 * w + p) * 64 + l) * 8]);
        #pragma unroll
        for (int rt = 0; rt < 4; ++rt)
            #pragma unroll
            for (int p = 0; p < 2; ++p)
                acc[rt][p] = __builtin_amdgcn_mfma_f32_16x16x32_bf16(
                    af[rt], bf[p], acc[rt][p], 0, 0, 0);
    }

    #pragma unroll
    for (int p = 0; p < 2; ++p) {
        int col = w * 32 + p * 16 + fr;
        float bs = b_skip[col];
        float s2 = stats[S_S2 + col];
        float t2 = stats[S_T2 + col];
        #pragma unroll
        for (int rt = 0; rt < 4; ++rt)
            #pragma unroll
            for (int j = 0; j < 4; ++j) {
                int n = n0 + rt * 16 + fq * 4 + j;
                if (n < N_ATOM) {
                    size_t o = (size_t)n * A_FEA + col;
                    float S = out[o];
                    out[o] = softplus_f(acc[rt][p][j] + bs + fmaf(S, s2, t2));
                }
            }
    }
}

// =====================================================================
// SLOW fallback path (round-2 validated code, unchanged)
// =====================================================================
#define BM 96
#define NTILES (ROWS/BM)
#define GRID_P 2500
#define TPB 256
#define APAD 328
#define ACTPAD 132

__global__ void prep_pack_slow(const float* __restrict__ Wfull,
                               const float* __restrict__ Wskip,
                               u16* __restrict__ wf, u16* __restrict__ wsf) {
    int tid = blockIdx.x * blockDim.x + threadIdx.x;
    if (tid < 10240) {
        int l = tid & 63;
        int ct = (tid >> 6) & 15;
        int kt = tid >> 10;
        int fr = l & 15, fq = l >> 4;
        int col = ct * 16 + fr;
        int k0 = kt * 32 + fq * 8;
        u16 tmp[8];
        #pragma unroll
        for (int i = 0; i < 8; ++i) tmp[i] = f2bf(Wfull[(k0 + i) * GDIM + col]);
        uint4 pk;
        pk.x = (u32)tmp[0] | ((u32)tmp[1] << 16);
        pk.y = (u32)tmp[2] | ((u32)tmp[3] << 16);
        pk.z = (u32)tmp[4] | ((u32)tmp[5] << 16);
        pk.w = (u32)tmp[6] | ((u32)tmp[7] << 16);
        *reinterpret_cast<uint4*>(&wf[tid * 8]) = pk;
    } else if (tid < 12288) {
        int t2 = tid - 10240;
        int l = t2 & 63;
        int ct = (t2 >> 6) & 7;
        int kt = t2 >> 9;
        int fr = l & 15, fq = l >> 4;
        int col = ct * 16 + fr;
        int k0 = kt * 32 + fq * 8;
        u16 tmp[8];
        #pragma unroll
        for (int i = 0; i < 8; ++i) tmp[i] = f2bf(Wskip[(k0 + i) * A_FEA + col]);
        uint4 pk;
        pk.x = (u32)tmp[0] | ((u32)tmp[1] << 16);
        pk.y = (u32)tmp[2] | ((u32)tmp[3] << 16);
        pk.z = (u32)tmp[4] | ((u32)tmp[5] << 16);
        pk.w = (u32)tmp[6] | ((u32)tmp[7] << 16);
        *reinterpret_cast<uint4*>(&wsf[t2 * 8]) = pk;
    }
}

template<int PASS>
__launch_bounds__(TPB, 2)
__global__ void pass_kernel(const float* __restrict__ atom_in,
                            const float* __restrict__ nbr_fea,
                            const int* __restrict__ nbr_idx,
                            const u16* __restrict__ wf,
                            float* __restrict__ stats,
                            float* __restrict__ out_ns) {
    __shared__ union {
        u16 a[BM * APAD];
        float act[BM * ACTPAD];
    } sh;

    const int t = threadIdx.x;
    const int w = t >> 6, l = t & 63, fr = l & 15, fq = l >> 4;
    const int ct0 = 2 * w;

    int colp[4];
    colp[0] = ct0 * 16 + fr;
    colp[1] = colp[0] + 16;
    colp[2] = colp[0] + 128;
    colp[3] = colp[1] + 128;

    float s1v[4], t1v[4];
    if (PASS == 2) {
        #pragma unroll
        for (int p = 0; p < 4; ++p) {
            s1v[p] = stats[S_S1 + colp[p]];
            t1v[p] = stats[S_T1 + colp[p]];
        }
    }
    float ls[4] = {0.f,0.f,0.f,0.f}, lq[4] = {0.f,0.f,0.f,0.f};
    float bsum = 0.f, bssq = 0.f;

    for (int tile = blockIdx.x; tile < NTILES; tile += GRID_P) {
        const int n0 = tile * 8;

        __syncthreads();
        for (int it = 0; it < 15; ++it) {
            int c = t + it * TPB;
            int row = c / 40;
            int seg = c - row * 40;
            int an = row / 12;
            int m  = row - an * 12;
            int na = n0 + an;
            const float* src;
            if (seg < 16) {
                src = atom_in + (size_t)na * A_FEA + seg * 8;
            } else if (seg < 32) {
                int j = nbr_idx[na * M_NBR + m];
                src = atom_in + (size_t)j * A_FEA + (seg - 16) * 8;
            } else {
                src = nbr_fea + ((size_t)na * M_NBR + m) * E_FEA + (seg - 32) * 8;
            }
            float4 x0 = *reinterpret_cast<const float4*>(src);
            float4 x1 = *reinterpret_cast<const float4*>(src + 4);
            uint4 pk;
            pk.x = (u32)f2bf(x0.x) | ((u32)f2bf(x0.y) << 16);
            pk.y = (u32)f2bf(x0.z) | ((u32)f2bf(x0.w) << 16);
            pk.z = (u32)f2bf(x1.x) | ((u32)f2bf(x1.y) << 16);
            pk.w = (u32)f2bf(x1.z) | ((u32)f2bf(x1.w) << 16);
            *reinterpret_cast<uint4*>(&sh.a[row * APAD + seg * 8]) = pk;
        }
        __syncthreads();

        f32x4 acc[6][4];
        #pragma unroll
        for (int rt = 0; rt < 6; ++rt)
            #pragma unroll
            for (int p = 0; p < 4; ++p)
                acc[rt][p] = (f32x4){0.f,0.f,0.f,0.f};

        for (int kt = 0; kt < 10; ++kt) {
            short8 af[6], bf[4];
            #pragma unroll
            for (int rt = 0; rt < 6; ++rt)
                af[rt] = *reinterpret_cast<const short8*>(
                    &sh.a[(rt * 16 + fr) * APAD + kt * 32 + fq * 8]);
            #pragma unroll
            for (int p = 0; p < 4; ++p) {
                int ct = (p < 2) ? (ct0 + p) : (ct0 + 8 + (p - 2));
                bf[p] = *reinterpret_cast<const short8*>(
                    &wf[((kt * 16 + ct) * 64 + l) * 8]);
            }
            #pragma unroll
            for (int rt = 0; rt < 6; ++rt)
                #pragma unroll
                for (int p = 0; p < 4; ++p)
                    acc[rt][p] = __builtin_amdgcn_mfma_f32_16x16x32_bf16(
                        af[rt], bf[p], acc[rt][p], 0, 0, 0);
        }

        if (PASS == 1) {
            #pragma unroll
            for (int p = 0; p < 4; ++p)
                #pragma unroll
                for (int rt = 0; rt < 6; ++rt)
                    #pragma unroll
                    for (int j = 0; j < 4; ++j) {
                        float v = acc[rt][p][j];
                        ls[p] += v;
                        lq[p] = fmaf(v, v, lq[p]);
                    }
        } else {
            __syncthreads();
            #pragma unroll
            for (int rt = 0; rt < 6; ++rt)
                #pragma unroll
                for (int p = 0; p < 2; ++p)
                    #pragma unroll
                    for (int j = 0; j < 4; ++j) {
                        float gf = fmaf(acc[rt][p][j],     s1v[p],     t1v[p]);
                        float gc = fmaf(acc[rt][2 + p][j], s1v[2 + p], t1v[2 + p]);
                        float a = sigmoid_f(gf) * softplus_f(gc);
                        int row = rt * 16 + fq * 4 + j;
                        int colact = ct0 * 16 + p * 16 + fr;
                        sh.act[row * ACTPAD + colact] = a;
                    }
            __syncthreads();
            #pragma unroll
            for (int i = 0; i < 4; ++i) {
                int o = i * TPB + t;
                int a = o >> 7;
                int c = o & 127;
                float S = 0.f;
                #pragma unroll
                for (int mm = 0; mm < 12; ++mm)
                    S += sh.act[(a * 12 + mm) * ACTPAD + c];
                out_ns[(size_t)(n0 + a) * A_FEA + c] = S;
                bsum += S;
                bssq = fmaf(S, S, bssq);
            }
        }
    }

    if (PASS == 1) {
        #pragma unroll
        for (int p = 0; p < 4; ++p) {
            float s = ls[p], q = lq[p];
            s += __shfl_xor(s, 16, 64);
            s += __shfl_xor(s, 32, 64);
            q += __shfl_xor(q, 16, 64);
            q += __shfl_xor(q, 32, 64);
            if (fq == 0) {
                atomicAdd(&stats[S_BN1SUM + colp[p]], s);
                atomicAdd(&stats[S_BN1SSQ + colp[p]], q);
            }
        }
    } else {
        __syncthreads();
        if (t >= 128) {
            sh.act[(t - 128) * 2]     = bsum;
            sh.act[(t - 128) * 2 + 1] = bssq;
        }
        __syncthreads();
        if (t < 128) {
            bsum += sh.act[t * 2];
            bssq += sh.act[t * 2 + 1];
            atomicAdd(&stats[S_BN2SUM + t], bsum);
            atomicAdd(&stats[S_BN2SSQ + t], bssq);
        }
    }
}

// =====================================================================
extern "C" void kernel_launch(void* const* d_in, const int* in_sizes, int n_in,
                              void* d_out, int out_size, void* d_ws, size_t ws_size,
                              hipStream_t stream) {
    (void)in_sizes; (void)n_in; (void)out_size;
    const float* atom_in = (const float*)d_in[0];
    const float* nbr_fea = (const float*)d_in[1];
    const int*   nbr_idx = (const int*)d_in[2];
    const float* Wfull   = (const float*)d_in[3];
    // d_in[4] = b_full: cancels exactly under batchnorm1 -> unused
    const float* g1      = (const float*)d_in[5];
    const float* b1      = (const float*)d_in[6];
    const float* g2      = (const float*)d_in[7];
    const float* b2      = (const float*)d_in[8];
    const float* Wsk     = (const float*)d_in[9];
    const float* bsk     = (const float*)d_in[10];
    float* out = (float*)d_out;

    float* stats = (float*)((char*)d_ws + STATS_OFF);
    u16* wskf = (u16*)((char*)d_ws + WSK_OFF);

    if (ws_size >= NEED_FAST3) {
        u16* wpq = (u16*)d_ws;
        u16* w3t = (u16*)((char*)d_ws + W3T_OFF);
        u16* Pb  = (u16*)((char*)d_ws + P_OFF);
        u16* Qb  = (u16*)((char*)d_ws + Q_OFF);

        zero_stats<<<1, 256, 0, stream>>>(stats);
        prep_pack2<<<48, 256, 0, stream>>>(Wfull, Wsk, wpq, w3t, wskf);
        pq_kernel<<<(N_ATOM + 63) / 64, 256, 0, stream>>>(atom_in, wpq, Pb, Qb);
        estage5<1><<<GRID_E, 512, 0, stream>>>(nbr_fea, nbr_idx, w3t, Pb, Qb, stats, out);
        finalize1<<<1, 256, 0, stream>>>(g1, b1, stats);
        estage5<2><<<GRID_E, 512, 0, stream>>>(nbr_fea, nbr_idx, w3t, Pb, Qb, stats, out);
        finalize2<<<1, 128, 0, stream>>>(g2, b2, stats);
        skip_kernel<<<(N_ATOM + BM5 - 1) / BM5, 256, 0, stream>>>(atom_in, wskf, bsk, stats, out);
    } else {
        u16* wf = (u16*)d_ws;
        zero_stats<<<1, 256, 0, stream>>>(stats);
        prep_pack_slow<<<48, 256, 0, stream>>>(Wfull, Wsk, wf, wskf);
        pass_kernel<1><<<GRID_P, TPB, 0, stream>>>(atom_in, nbr_fea, nbr_idx, wf, stats, out);
        finalize1<<<1, 256, 0, stream>>>(g1, b1, stats);
        pass_kernel<2><<<GRID_P, TPB, 0, stream>>>(atom_in, nbr_fea, nbr_idx, wf, stats, out);
        finalize2<<<1, 128, 0, stream>>>(g2, b2, stats);
        skip_kernel<<<(N_ATOM + BM5 - 1) / BM5, 256, 0, stream>>>(atom_in, wskf, bsk, stats, out);
    }
}

// Round 9
// 1027.264 us; speedup vs baseline: 1.7548x; 1.0902x over previous
//
#include <hip/hip_runtime.h>
#include <stdint.h>

#define N_ATOM 100000
#define M_NBR 12
#define A_FEA 128
#define E_FEA 64
#define KDIM 320
#define GDIM 256
#define ROWS (N_ATOM*M_NBR)
#define BN_EPS 1e-5f

typedef unsigned short u16;
typedef unsigned int u32;
typedef __attribute__((ext_vector_type(8))) short short8;
typedef __attribute__((ext_vector_type(4))) float f32x4;

// ---- stats slot indices (floats) ----
#define S_BN1SUM 0
#define S_BN1SSQ 256
#define S_S1 512
#define S_T1 768
#define S_BN2SUM 1024
#define S_BN2SSQ 1152
#define S_S2 1280
#define S_T2 1408
#define STATS_F32 1536

// ---- workspace layout ----
#define WPQ_OFF 0
#define W3T_OFF 131072
#define WSK_OFF 163840
#define STATS_OFF 196608
#define P_OFF 202752
#define PQ_BYTES ((size_t)N_ATOM*256*2)            // 51,200,000
#define Q_OFF (P_OFF + PQ_BYTES)
#define NEED_FAST3 (P_OFF + 2*PQ_BYTES)            // ~102.6 MB

__device__ __forceinline__ u16 f2bf(float x) {
    union { float f; u32 u; } v; v.f = x;
    u32 r = v.u + 0x7FFFu + ((v.u >> 16) & 1u);
    return (u16)(r >> 16);
}
__device__ __forceinline__ float bflo(u32 x) { return __uint_as_float(x << 16); }
__device__ __forceinline__ float bfhi(u32 x) { return __uint_as_float(x & 0xFFFF0000u); }
__device__ __forceinline__ float softplus_f(float x) {
    return fmaxf(x, 0.f) + __logf(1.f + __expf(-fabsf(x)));
}
__device__ __forceinline__ float sigmoid_f(float x) {
    return 1.f / (1.f + __expf(-x));
}

// Zero bn accumulators every launch (plain kernel -> always a graph node).
__global__ void zero_stats(float* __restrict__ stats) {
    int t = threadIdx.x;              // 256
    stats[t] = 0.f;
    stats[256 + t] = 0.f;
    stats[1024 + t] = 0.f;
}

__global__ void finalize1(const float* __restrict__ g1, const float* __restrict__ b1,
                          float* __restrict__ stats) {
    int c = threadIdx.x;  // 256
    const float inv_cnt = 1.f / (float)ROWS;
    float mean = stats[S_BN1SUM + c] * inv_cnt;
    float var  = stats[S_BN1SSQ + c] * inv_cnt - mean * mean;
    float iv = rsqrtf(var + BN_EPS);
    float s = g1[c] * iv;
    stats[S_S1 + c] = s;
    stats[S_T1 + c] = fmaf(-mean, s, b1[c]);
}

__global__ void finalize2(const float* __restrict__ g2, const float* __restrict__ b2,
                          float* __restrict__ stats) {
    int c = threadIdx.x;  // 128
    const float inv_cnt = 1.f / (float)N_ATOM;
    float mean = stats[S_BN2SUM + c] * inv_cnt;
    float var  = stats[S_BN2SSQ + c] * inv_cnt - mean * mean;
    float iv = rsqrtf(var + BN_EPS);
    float s = g2[c] * iv;
    stats[S_S2 + c] = s;
    stats[S_T2 + c] = fmaf(-mean, s, b2[c]);
}

// Pack Wpq (B for P/Q GEMM: 128 x 512), W3T (A-frags of W3^T: 256 x 64),
// Wsk (128 x 128) into MFMA fragment order.
__global__ void prep_pack2(const float* __restrict__ Wfull,
                           const float* __restrict__ Wskip,
                           u16* __restrict__ wpq, u16* __restrict__ w3t,
                           u16* __restrict__ wsk) {
    int tid = blockIdx.x * blockDim.x + threadIdx.x;
    int l = tid & 63, fr = l & 15, fq = l >> 4;
    if (tid < 8192) {
        int ct = (tid >> 6) & 31;
        int kt = tid >> 11;                 // 0..3
        int c = ct * 16 + fr;               // 0..511
        int k0 = kt * 32 + fq * 8;          // 0..127
        u16 tmp[8];
        #pragma unroll
        for (int i = 0; i < 8; ++i) {
            int kk = k0 + i;
            float v = (c < 256) ? Wfull[kk * GDIM + c]
                                : Wfull[(128 + kk) * GDIM + (c - 256)];
            tmp[i] = f2bf(v);
        }
        uint4 pk;
        pk.x = (u32)tmp[0] | ((u32)tmp[1] << 16);
        pk.y = (u32)tmp[2] | ((u32)tmp[3] << 16);
        pk.z = (u32)tmp[4] | ((u32)tmp[5] << 16);
        pk.w = (u32)tmp[6] | ((u32)tmp[7] << 16);
        *reinterpret_cast<uint4*>(&wpq[tid * 8]) = pk;
    } else if (tid < 10240) {
        // W3T A-frag: frag=(kt*16+rt16), elem i -> Wfull[256+kt*32+fq*8+i][rt16*16+fr]
        int t2 = tid - 8192;               // 0..2047
        int frag = t2 >> 6;                // 0..31
        int rt16 = frag & 15, kt = frag >> 4;
        int gcol = rt16 * 16 + fr;
        int k0 = kt * 32 + fq * 8;
        u16 tmp[8];
        #pragma unroll
        for (int i = 0; i < 8; ++i) tmp[i] = f2bf(Wfull[(256 + k0 + i) * GDIM + gcol]);
        uint4 pk;
        pk.x = (u32)tmp[0] | ((u32)tmp[1] << 16);
        pk.y = (u32)tmp[2] | ((u32)tmp[3] << 16);
        pk.z = (u32)tmp[4] | ((u32)tmp[5] << 16);
        pk.w = (u32)tmp[6] | ((u32)tmp[7] << 16);
        *reinterpret_cast<uint4*>(&w3t[t2 * 8]) = pk;
    } else if (tid < 12288) {
        int t3 = tid - 10240;
        int ct = (t3 >> 6) & 7;
        int kt = t3 >> 9;                   // 0..3
        int c = ct * 16 + fr;
        int k0 = kt * 32 + fq * 8;
        u16 tmp[8];
        #pragma unroll
        for (int i = 0; i < 8; ++i) tmp[i] = f2bf(Wskip[(k0 + i) * A_FEA + c]);
        uint4 pk;
        pk.x = (u32)tmp[0] | ((u32)tmp[1] << 16);
        pk.y = (u32)tmp[2] | ((u32)tmp[3] << 16);
        pk.z = (u32)tmp[4] | ((u32)tmp[5] << 16);
        pk.w = (u32)tmp[6] | ((u32)tmp[7] << 16);
        *reinterpret_cast<uint4*>(&wsk[t3 * 8]) = pk;
    }
}

// P[n] = atom_in[n] @ Wfull[0:128];  Q[n] = atom_in[n] @ Wfull[128:256]
__launch_bounds__(256)
__global__ void pq_kernel(const float* __restrict__ atom_in,
                          const u16* __restrict__ wpq,
                          u16* __restrict__ Pb, u16* __restrict__ Qb) {
    __shared__ u16 al[64 * 130];
    const int t = threadIdx.x;
    const int w = t >> 6, l = t & 63, fr = l & 15, fq = l >> 4;
    const int n0 = blockIdx.x * 64;

    #pragma unroll
    for (int it = 0; it < 4; ++it) {
        int c = t + it * 256;         // 0..1023
        int row = c >> 4, seg = c & 15;
        int n = n0 + row;
        uint4 pk = {0u, 0u, 0u, 0u};
        if (n < N_ATOM) {
            const float* src = atom_in + (size_t)n * A_FEA + seg * 8;
            float4 x0 = *reinterpret_cast<const float4*>(src);
            float4 x1 = *reinterpret_cast<const float4*>(src + 4);
            pk.x = (u32)f2bf(x0.x) | ((u32)f2bf(x0.y) << 16);
            pk.y = (u32)f2bf(x0.z) | ((u32)f2bf(x0.w) << 16);
            pk.z = (u32)f2bf(x1.x) | ((u32)f2bf(x1.y) << 16);
            pk.w = (u32)f2bf(x1.z) | ((u32)f2bf(x1.w) << 16);
        }
        *reinterpret_cast<uint4*>(&al[row * 130 + seg * 8]) = pk;
    }
    __syncthreads();

    f32x4 acc[4][8];
    #pragma unroll
    for (int rt = 0; rt < 4; ++rt)
        #pragma unroll
        for (int p = 0; p < 8; ++p)
            acc[rt][p] = (f32x4){0.f,0.f,0.f,0.f};

    for (int kt = 0; kt < 4; ++kt) {
        short8 af[4], bf[8];
        #pragma unroll
        for (int rt = 0; rt < 4; ++rt)
            af[rt] = *reinterpret_cast<const short8*>(
                &al[(rt * 16 + fr) * 130 + kt * 32 + fq * 8]);
        #pragma unroll
        for (int p = 0; p < 8; ++p)
            bf[p] = *reinterpret_cast<const short8*>(
                &wpq[((kt * 32 + w * 8 + p) * 64 + l) * 8]);
        #pragma unroll
        for (int rt = 0; rt < 4; ++rt)
            #pragma unroll
            for (int p = 0; p < 8; ++p)
                acc[rt][p] = __builtin_amdgcn_mfma_f32_16x16x32_bf16(
                    af[rt], bf[p], acc[rt][p], 0, 0, 0);
    }

    #pragma unroll
    for (int p = 0; p < 8; ++p) {
        int col = w * 128 + p * 16 + fr;            // 0..511
        u16* dst = (col < 256) ? Pb : Qb;
        int cc = (col < 256) ? col : (col - 256);
        #pragma unroll
        for (int rt = 0; rt < 4; ++rt)
            #pragma unroll
            for (int j = 0; j < 4; ++j) {
                int n = n0 + rt * 16 + fq * 4 + j;
                if (n < N_ATOM) dst[(size_t)n * 256 + cc] = f2bf(acc[rt][p][j]);
            }
    }
}

// =====================================================================
// Edge kernel v5: transposed MFMA + inline f32->bf16 staging.
// __launch_bounds__(512, 2): LDS (68.6KB) caps occupancy at 2 blocks/CU
// anyway; min-waves=4 capped VGPRs at 64 and spilled ~1 GB/dispatch (R8).
// =====================================================================
#define NTILES_E (ROWS/96)     // 12500
#define GRID_E 2500
#define EPAD 66                // u16 stride of nbr tile rows
#define PPAD2 264              // u16 stride of P rows
#define QPAD2 268              // u16 stride of Q rows
#define ACT2 132               // f32 stride of act rows
#define E_SH (96*EPAD*2)                // 12672
#define P_SH0 E_SH                      // p at +12672 (4224 B)
#define Q_SH0 (E_SH + 8*PPAD2*2)        // q at +16896 (51456 B)
#define SH_TOT (Q_SH0 + 96*QPAD2*2)     // 68352; act overlay 96*132*4=50688 <= 51456

template<int MODE>
__launch_bounds__(512, 2)
__global__ void estage5(const float* __restrict__ nbr_fea,
                        const int* __restrict__ nbr_idx,
                        const u16* __restrict__ w3t,
                        const u16* __restrict__ Pb,
                        const u16* __restrict__ Qb,
                        float* __restrict__ stats,
                        float* __restrict__ out_ns) {
    __shared__ __align__(16) unsigned char shraw[SH_TOT];
    u16* e_lds = (u16*)shraw;
    u16* p_lds = (u16*)(shraw + P_SH0);
    u16* q_lds = (u16*)(shraw + Q_SH0);
    float* act = (float*)(shraw + Q_SH0);
    float* red = (float*)shraw;

    const int t = threadIdx.x;
    const int w = t >> 6, l = t & 63, fr = l & 15, fq = l >> 4;
    const int gbase0 = w * 16 + fq * 4;        // filter col base (rt=0); core = +128

    // Tile-invariant W3^T A-fragments.
    short8 aw[2][2];
    #pragma unroll
    for (int kt = 0; kt < 2; ++kt)
        #pragma unroll
        for (int rt = 0; rt < 2; ++rt)
            aw[kt][rt] = *reinterpret_cast<const short8*>(
                &w3t[(((kt * 16) + w + rt * 8) * 64 + l) * 8]);

    float s1v[2][4], t1v[2][4];
    if (MODE == 2) {
        #pragma unroll
        for (int rt = 0; rt < 2; ++rt)
            #pragma unroll
            for (int j = 0; j < 4; ++j) {
                int col = gbase0 + rt * 128 + j;
                s1v[rt][j] = stats[S_S1 + col];
                t1v[rt][j] = stats[S_T1 + col];
            }
    }
    float ls[2][4] = {{0,0,0,0},{0,0,0,0}}, lq[2][4] = {{0,0,0,0},{0,0,0,0}};
    float bsum = 0.f, bssq = 0.f;

    for (int tile = blockIdx.x; tile < NTILES_E; tile += GRID_E) {
        const int r0 = tile * 96;
        const int n0a = tile * 8;

        __syncthreads();   // protect LDS from previous-iteration readers

        // ---- stage nbr tile: 96 x 64 f32 -> bf16 (plain cached loads) ----
        #pragma unroll
        for (int i = 0; i < 2; ++i) {
            int o = t + i * 512;
            if (o < 768) {
                int row = o >> 3, seg = o & 7;
                const float* src = nbr_fea + (size_t)(r0 + row) * E_FEA + seg * 8;
                float4 x0 = *reinterpret_cast<const float4*>(src);
                float4 x1 = *reinterpret_cast<const float4*>(src + 4);
                uint4 pk;
                pk.x = (u32)f2bf(x0.x) | ((u32)f2bf(x0.y) << 16);
                pk.y = (u32)f2bf(x0.z) | ((u32)f2bf(x0.w) << 16);
                pk.z = (u32)f2bf(x1.x) | ((u32)f2bf(x1.y) << 16);
                pk.w = (u32)f2bf(x1.z) | ((u32)f2bf(x1.w) << 16);
                *reinterpret_cast<uint4*>(&e_lds[row * EPAD + seg * 8]) = pk;
            }
        }
        // ---- stage P rows: 8 x 256 bf16 ----
        if (t < 256) {
            int row = t >> 5, seg = t & 31;
            *reinterpret_cast<uint4*>(&p_lds[row * PPAD2 + seg * 8]) =
                *reinterpret_cast<const uint4*>(&Pb[(size_t)(n0a + row) * 256 + seg * 8]);
        }
        // ---- stage Q[idx]: 96 rows, one row per wave-iter, 512B bursts ----
        #pragma unroll
        for (int i = 0; i < 12; ++i) {
            int row = i * 8 + w;
            int jr = nbr_idx[r0 + row];
            *reinterpret_cast<uint2*>(&q_lds[row * QPAD2 + l * 4]) =
                *reinterpret_cast<const uint2*>(&Qb[(size_t)jr * 256 + l * 4]);
        }
        __syncthreads();

        // ---- MFMA: gated^T tile, acc[rt][ct] ----
        f32x4 acc[2][6];
        #pragma unroll
        for (int rt = 0; rt < 2; ++rt)
            #pragma unroll
            for (int ct = 0; ct < 6; ++ct)
                acc[rt][ct] = (f32x4){0.f,0.f,0.f,0.f};
        #pragma unroll
        for (int kt = 0; kt < 2; ++kt) {
            short8 bf[6];
            #pragma unroll
            for (int ct = 0; ct < 6; ++ct)
                bf[ct] = *reinterpret_cast<const short8*>(
                    &e_lds[(ct * 16 + fr) * EPAD + kt * 32 + fq * 8]);
            #pragma unroll
            for (int rt = 0; rt < 2; ++rt)
                #pragma unroll
                for (int ct = 0; ct < 6; ++ct)
                    acc[rt][ct] = __builtin_amdgcn_mfma_f32_16x16x32_bf16(
                        aw[kt][rt], bf[ct], acc[rt][ct], 0, 0, 0);
        }

        if (MODE == 1) {
            #pragma unroll
            for (int ct = 0; ct < 6; ++ct) {
                int edge = ct * 16 + fr;
                int atom = (edge * 171) >> 11;     // edge/12
                uint2 qv0 = *reinterpret_cast<const uint2*>(&q_lds[edge * QPAD2 + gbase0]);
                uint2 qv1 = *reinterpret_cast<const uint2*>(&q_lds[edge * QPAD2 + gbase0 + 128]);
                uint2 pv0 = *reinterpret_cast<const uint2*>(&p_lds[atom * PPAD2 + gbase0]);
                uint2 pv1 = *reinterpret_cast<const uint2*>(&p_lds[atom * PPAD2 + gbase0 + 128]);
                float g;
                g = acc[0][ct][0] + bflo(qv0.x) + bflo(pv0.x); ls[0][0] += g; lq[0][0] = fmaf(g,g,lq[0][0]);
                g = acc[0][ct][1] + bfhi(qv0.x) + bfhi(pv0.x); ls[0][1] += g; lq[0][1] = fmaf(g,g,lq[0][1]);
                g = acc[0][ct][2] + bflo(qv0.y) + bflo(pv0.y); ls[0][2] += g; lq[0][2] = fmaf(g,g,lq[0][2]);
                g = acc[0][ct][3] + bfhi(qv0.y) + bfhi(pv0.y); ls[0][3] += g; lq[0][3] = fmaf(g,g,lq[0][3]);
                g = acc[1][ct][0] + bflo(qv1.x) + bflo(pv1.x); ls[1][0] += g; lq[1][0] = fmaf(g,g,lq[1][0]);
                g = acc[1][ct][1] + bfhi(qv1.x) + bfhi(pv1.x); ls[1][1] += g; lq[1][1] = fmaf(g,g,lq[1][1]);
                g = acc[1][ct][2] + bflo(qv1.y) + bflo(pv1.y); ls[1][2] += g; lq[1][2] = fmaf(g,g,lq[1][2]);
                g = acc[1][ct][3] + bfhi(qv1.y) + bfhi(pv1.y); ls[1][3] += g; lq[1][3] = fmaf(g,g,lq[1][3]);
            }
        } else {
            float ar[6][4];
            #pragma unroll
            for (int ct = 0; ct < 6; ++ct) {
                int edge = ct * 16 + fr;
                int atom = (edge * 171) >> 11;
                uint2 qv0 = *reinterpret_cast<const uint2*>(&q_lds[edge * QPAD2 + gbase0]);
                uint2 qv1 = *reinterpret_cast<const uint2*>(&q_lds[edge * QPAD2 + gbase0 + 128]);
                uint2 pv0 = *reinterpret_cast<const uint2*>(&p_lds[atom * PPAD2 + gbase0]);
                uint2 pv1 = *reinterpret_cast<const uint2*>(&p_lds[atom * PPAD2 + gbase0 + 128]);
                float gf, gc;
                gf = acc[0][ct][0] + bflo(qv0.x) + bflo(pv0.x);
                gc = acc[1][ct][0] + bflo(qv1.x) + bflo(pv1.x);
                ar[ct][0] = sigmoid_f(fmaf(gf, s1v[0][0], t1v[0][0])) * softplus_f(fmaf(gc, s1v[1][0], t1v[1][0]));
                gf = acc[0][ct][1] + bfhi(qv0.x) + bfhi(pv0.x);
                gc = acc[1][ct][1] + bfhi(qv1.x) + bfhi(pv1.x);
                ar[ct][1] = sigmoid_f(fmaf(gf, s1v[0][1], t1v[0][1])) * softplus_f(fmaf(gc, s1v[1][1], t1v[1][1]));
                gf = acc[0][ct][2] + bflo(qv0.y) + bflo(pv0.y);
                gc = acc[1][ct][2] + bflo(qv1.y) + bflo(pv1.y);
                ar[ct][2] = sigmoid_f(fmaf(gf, s1v[0][2], t1v[0][2])) * softplus_f(fmaf(gc, s1v[1][2], t1v[1][2]));
                gf = acc[0][ct][3] + bfhi(qv0.y) + bfhi(pv0.y);
                gc = acc[1][ct][3] + bfhi(qv1.y) + bfhi(pv1.y);
                ar[ct][3] = sigmoid_f(fmaf(gf, s1v[0][3], t1v[0][3])) * softplus_f(fmaf(gc, s1v[1][3], t1v[1][3]));
            }
            __syncthreads();   // everyone done reading q_lds; act overlays it
            #pragma unroll
            for (int ct = 0; ct < 6; ++ct) {
                int edge = ct * 16 + fr;
                float4 f4 = make_float4(ar[ct][0], ar[ct][1], ar[ct][2], ar[ct][3]);
                *reinterpret_cast<float4*>(&act[edge * ACT2 + gbase0]) = f4;
            }
            __syncthreads();
            // m-sum -> nbr_sumed -> out; bn2 stats
            #pragma unroll
            for (int i = 0; i < 2; ++i) {
                int o = i * 512 + t;
                int a = o >> 7;            // atom 0..7
                int c = t & 127;
                float S = 0.f;
                #pragma unroll
                for (int mm = 0; mm < 12; ++mm)
                    S += act[(a * 12 + mm) * ACT2 + c];
                out_ns[(size_t)(n0a + a) * A_FEA + c] = S;
                bsum += S;
                bssq = fmaf(S, S, bssq);
            }
        }
    }

    if (MODE == 1) {
        #pragma unroll
        for (int rt = 0; rt < 2; ++rt)
            #pragma unroll
            for (int j = 0; j < 4; ++j) {
                float s = ls[rt][j], q = lq[rt][j];
                s += __shfl_xor(s, 1, 64);  s += __shfl_xor(s, 2, 64);
                s += __shfl_xor(s, 4, 64);  s += __shfl_xor(s, 8, 64);
                q += __shfl_xor(q, 1, 64);  q += __shfl_xor(q, 2, 64);
                q += __shfl_xor(q, 4, 64);  q += __shfl_xor(q, 8, 64);
                if (fr == 0) {
                    int col = gbase0 + rt * 128 + j;
                    atomicAdd(&stats[S_BN1SUM + col], s);
                    atomicAdd(&stats[S_BN1SSQ + col], q);
                }
            }
    } else {
        __syncthreads();
        if (t >= 128) {
            red[(t - 128) * 2]     = bsum;
            red[(t - 128) * 2 + 1] = bssq;
        }
        __syncthreads();
        if (t < 128) {
            bsum += red[t * 2]     + red[(128 + t) * 2]     + red[(256 + t) * 2];
            bssq += red[t * 2 + 1] + red[(128 + t) * 2 + 1] + red[(256 + t) * 2 + 1];
            atomicAdd(&stats[S_BN2SUM + t], bsum);
            atomicAdd(&stats[S_BN2SSQ + t], bssq);
        }
    }
}

// Skip GEMM + bn2 affine + softplus (in place on out).
#define BM5 64
__launch_bounds__(256, 2)
__global__ void skip_kernel(const float* __restrict__ atom_in,
                            const u16* __restrict__ wsf,
                            const float* __restrict__ b_skip,
                            const float* __restrict__ stats,
                            float* __restrict__ out) {
    __shared__ u16 a5[BM5 * 136];
    const int t = threadIdx.x;
    const int w = t >> 6, l = t & 63, fr = l & 15, fq = l >> 4;
    const int n0 = blockIdx.x * BM5;

    #pragma unroll
    for (int it = 0; it < 4; ++it) {
        int c = t + it * 256;
        int row = c >> 4, seg = c & 15;
        int n = n0 + row;
        uint4 pk = {0u, 0u, 0u, 0u};
        if (n < N_ATOM) {
            const float* src = atom_in + (size_t)n * A_FEA + seg * 8;
            float4 x0 = *reinterpret_cast<const float4*>(src);
            float4 x1 = *reinterpret_cast<const float4*>(src + 4);
            pk.x = (u32)f2bf(x0.x) | ((u32)f2bf(x0.y) << 16);
            pk.y = (u32)f2bf(x0.z) | ((u32)f2bf(x0.w) << 16);
            pk.z = (u32)f2bf(x1.x) | ((u32)f2bf(x1.y) << 16);
            pk.w = (u32)f2bf(x1.z) | ((u32)f2bf(x1.w) << 16);
        }
        *reinterpret_cast<uint4*>(&a5[row * 136 + seg * 8]) = pk;
    }
    __syncthreads();

    f32x4 acc[4][2];
    #pragma unroll
    for (int rt = 0; rt < 4; ++rt) {
        acc[rt][0] = (f32x4){0.f,0.f,0.f,0.f};
        acc[rt][1] = (f32x4){0.f,0.f,0.f,0.f};
    }
    for (int kt = 0; kt < 4; ++kt) {
        short8 af[4], bf[2];
        #pragma unroll
        for (int rt = 0; rt < 4; ++rt)
            af[rt] = *reinterpret_cast<const short8*>(
                &a5[(rt * 16 + fr) * 136 + kt * 32 + fq * 8]);
        #pragma unroll
        for (int p = 0; p < 2; ++p)
            bf[p] = *reinterpret_cast<const short8*>(
                &wsf[((kt * 8 + 2 * w + p) * 64 + l) * 8]);
        #pragma unroll
        for (int rt = 0; rt < 4; ++rt)
            #pragma unroll
            for (int p = 0; p < 2; ++p)
                acc[rt][p] = __builtin_amdgcn_mfma_f32_16x16x32_bf16(
                    af[rt], bf[p], acc[rt][p], 0, 0, 0);
    }

    #pragma unroll
    for (int p = 0; p < 2; ++p) {
        int col = w * 32 + p * 16 + fr;
        float bs = b_skip[col];
        float s2 = stats[S_S2 + col];
        float t2 = stats[S_T2 + col];
        #pragma unroll
        for (int rt = 0; rt < 4; ++rt)
            #pragma unroll
            for (int j = 0; j < 4; ++j) {
                int n = n0 + rt * 16 + fq * 4 + j;
                if (n < N_ATOM) {
                    size_t o = (size_t)n * A_FEA + col;
                    float S = out[o];
                    out[o] = softplus_f(acc[rt][p][j] + bs + fmaf(S, s2, t2));
                }
            }
    }
}

// =====================================================================
// SLOW fallback path (round-2 validated code, unchanged)
// =====================================================================
#define BM 96
#define NTILES (ROWS/BM)
#define GRID_P 2500
#define TPB 256
#define APAD 328
#define ACTPAD 132

__global__ void prep_pack_slow(const float* __restrict__ Wfull,
                               const float* __restrict__ Wskip,
                               u16* __restrict__ wf, u16* __restrict__ wsf) {
    int tid = blockIdx.x * blockDim.x + threadIdx.x;
    if (tid < 10240) {
        int l = tid & 63;
        int ct = (tid >> 6) & 15;
        int kt = tid >> 10;
        int fr = l & 15, fq = l >> 4;
        int col = ct * 16 + fr;
        int k0 = kt * 32 + fq * 8;
        u16 tmp[8];
        #pragma unroll
        for (int i = 0; i < 8; ++i) tmp[i] = f2bf(Wfull[(k0 + i) * GDIM + col]);
        uint4 pk;
        pk.x = (u32)tmp[0] | ((u32)tmp[1] << 16);
        pk.y = (u32)tmp[2] | ((u32)tmp[3] << 16);
        pk.z = (u32)tmp[4] | ((u32)tmp[5] << 16);
        pk.w = (u32)tmp[6] | ((u32)tmp[7] << 16);
        *reinterpret_cast<uint4*>(&wf[tid * 8]) = pk;
    } else if (tid < 12288) {
        int t2 = tid - 10240;
        int l = t2 & 63;
        int ct = (t2 >> 6) & 7;
        int kt = t2 >> 9;
        int fr = l & 15, fq = l >> 4;
        int col = ct * 16 + fr;
        int k0 = kt * 32 + fq * 8;
        u16 tmp[8];
        #pragma unroll
        for (int i = 0; i < 8; ++i) tmp[i] = f2bf(Wskip[(k0 + i) * A_FEA + col]);
        uint4 pk;
        pk.x = (u32)tmp[0] | ((u32)tmp[1] << 16);
        pk.y = (u32)tmp[2] | ((u32)tmp[3] << 16);
        pk.z = (u32)tmp[4] | ((u32)tmp[5] << 16);
        pk.w = (u32)tmp[6] | ((u32)tmp[7] << 16);
        *reinterpret_cast<uint4*>(&wsf[t2 * 8]) = pk;
    }
}

template<int PASS>
__launch_bounds__(TPB, 2)
__global__ void pass_kernel(const float* __restrict__ atom_in,
                            const float* __restrict__ nbr_fea,
                            const int* __restrict__ nbr_idx,
                            const u16* __restrict__ wf,
                            float* __restrict__ stats,
                            float* __restrict__ out_ns) {
    __shared__ union {
        u16 a[BM * APAD];
        float act[BM * ACTPAD];
    } sh;

    const int t = threadIdx.x;
    const int w = t >> 6, l = t & 63, fr = l & 15, fq = l >> 4;
    const int ct0 = 2 * w;

    int colp[4];
    colp[0] = ct0 * 16 + fr;
    colp[1] = colp[0] + 16;
    colp[2] = colp[0] + 128;
    colp[3] = colp[1] + 128;

    float s1v[4], t1v[4];
    if (PASS == 2) {
        #pragma unroll
        for (int p = 0; p < 4; ++p) {
            s1v[p] = stats[S_S1 + colp[p]];
            t1v[p] = stats[S_T1 + colp[p]];
        }
    }
    float ls[4] = {0.f,0.f,0.f,0.f}, lq[4] = {0.f,0.f,0.f,0.f};
    float bsum = 0.f, bssq = 0.f;

    for (int tile = blockIdx.x; tile < NTILES; tile += GRID_P) {
        const int n0 = tile * 8;

        __syncthreads();
        for (int it = 0; it < 15; ++it) {
            int c = t + it * TPB;
            int row = c / 40;
            int seg = c - row * 40;
            int an = row / 12;
            int m  = row - an * 12;
            int na = n0 + an;
            const float* src;
            if (seg < 16) {
                src = atom_in + (size_t)na * A_FEA + seg * 8;
            } else if (seg < 32) {
                int j = nbr_idx[na * M_NBR + m];
                src = atom_in + (size_t)j * A_FEA + (seg - 16) * 8;
            } else {
                src = nbr_fea + ((size_t)na * M_NBR + m) * E_FEA + (seg - 32) * 8;
            }
            float4 x0 = *reinterpret_cast<const float4*>(src);
            float4 x1 = *reinterpret_cast<const float4*>(src + 4);
            uint4 pk;
            pk.x = (u32)f2bf(x0.x) | ((u32)f2bf(x0.y) << 16);
            pk.y = (u32)f2bf(x0.z) | ((u32)f2bf(x0.w) << 16);
            pk.z = (u32)f2bf(x1.x) | ((u32)f2bf(x1.y) << 16);
            pk.w = (u32)f2bf(x1.z) | ((u32)f2bf(x1.w) << 16);
            *reinterpret_cast<uint4*>(&sh.a[row * APAD + seg * 8]) = pk;
        }
        __syncthreads();

        f32x4 acc[6][4];
        #pragma unroll
        for (int rt = 0; rt < 6; ++rt)
            #pragma unroll
            for (int p = 0; p < 4; ++p)
                acc[rt][p] = (f32x4){0.f,0.f,0.f,0.f};

        for (int kt = 0; kt < 10; ++kt) {
            short8 af[6], bf[4];
            #pragma unroll
            for (int rt = 0; rt < 6; ++rt)
                af[rt] = *reinterpret_cast<const short8*>(
                    &sh.a[(rt * 16 + fr) * APAD + kt * 32 + fq * 8]);
            #pragma unroll
            for (int p = 0; p < 4; ++p) {
                int ct = (p < 2) ? (ct0 + p) : (ct0 + 8 + (p - 2));
                bf[p] = *reinterpret_cast<const short8*>(
                    &wf[((kt * 16 + ct) * 64 + l) * 8]);
            }
            #pragma unroll
            for (int rt = 0; rt < 6; ++rt)
                #pragma unroll
                for (int p = 0; p < 4; ++p)
                    acc[rt][p] = __builtin_amdgcn_mfma_f32_16x16x32_bf16(
                        af[rt], bf[p], acc[rt][p], 0, 0, 0);
        }

        if (PASS == 1) {
            #pragma unroll
            for (int p = 0; p < 4; ++p)
                #pragma unroll
                for (int rt = 0; rt < 6; ++rt)
                    #pragma unroll
                    for (int j = 0; j < 4; ++j) {
                        float v = acc[rt][p][j];
                        ls[p] += v;
                        lq[p] = fmaf(v, v, lq[p]);
                    }
        } else {
            __syncthreads();
            #pragma unroll
            for (int rt = 0; rt < 6; ++rt)
                #pragma unroll
                for (int p = 0; p < 2; ++p)
                    #pragma unroll
                    for (int j = 0; j < 4; ++j) {
                        float gf = fmaf(acc[rt][p][j],     s1v[p],     t1v[p]);
                        float gc = fmaf(acc[rt][2 + p][j], s1v[2 + p], t1v[2 + p]);
                        float a = sigmoid_f(gf) * softplus_f(gc);
                        int row = rt * 16 + fq * 4 + j;
                        int colact = ct0 * 16 + p * 16 + fr;
                        sh.act[row * ACTPAD + colact] = a;
                    }
            __syncthreads();
            #pragma unroll
            for (int i = 0; i < 4; ++i) {
                int o = i * TPB + t;
                int a = o >> 7;
                int c = o & 127;
                float S = 0.f;
                #pragma unroll
                for (int mm = 0; mm < 12; ++mm)
                    S += sh.act[(a * 12 + mm) * ACTPAD + c];
                out_ns[(size_t)(n0 + a) * A_FEA + c] = S;
                bsum += S;
                bssq = fmaf(S, S, bssq);
            }
        }
    }

    if (PASS == 1) {
        #pragma unroll
        for (int p = 0; p < 4; ++p) {
            float s = ls[p], q = lq[p];
            s += __shfl_xor(s, 16, 64);
            s += __shfl_xor(s, 32, 64);
            q += __shfl_xor(q, 16, 64);
            q += __shfl_xor(q, 32, 64);
            if (fq == 0) {
                atomicAdd(&stats[S_BN1SUM + colp[p]], s);
                atomicAdd(&stats[S_BN1SSQ + colp[p]], q);
            }
        }
    } else {
        __syncthreads();
        if (t >= 128) {
            sh.act[(t - 128) * 2]     = bsum;
            sh.act[(t - 128) * 2 + 1] = bssq;
        }
        __syncthreads();
        if (t < 128) {
            bsum += sh.act[t * 2];
            bssq += sh.act[t * 2 + 1];
            atomicAdd(&stats[S_BN2SUM + t], bsum);
            atomicAdd(&stats[S_BN2SSQ + t], bssq);
        }
    }
}

// =====================================================================
extern "C" void kernel_launch(void* const* d_in, const int* in_sizes, int n_in,
                              void* d_out, int out_size, void* d_ws, size_t ws_size,
                              hipStream_t stream) {
    (void)in_sizes; (void)n_in; (void)out_size;
    const float* atom_in = (const float*)d_in[0];
    const float* nbr_fea = (const float*)d_in[1];
    const int*   nbr_idx = (const int*)d_in[2];
    const float* Wfull   = (const float*)d_in[3];
    // d_in[4] = b_full: cancels exactly under batchnorm1 -> unused
    const float* g1      = (const float*)d_in[5];
    const float* b1      = (const float*)d_in[6];
    const float* g2      = (const float*)d_in[7];
    const float* b2      = (const float*)d_in[8];
    const float* Wsk     = (const float*)d_in[9];
    const float* bsk     = (const float*)d_in[10];
    float* out = (float*)d_out;

    float* stats = (float*)((char*)d_ws + STATS_OFF);
    u16* wskf = (u16*)((char*)d_ws + WSK_OFF);

    if (ws_size >= NEED_FAST3) {
        u16* wpq = (u16*)d_ws;
        u16* w3t = (u16*)((char*)d_ws + W3T_OFF);
        u16* Pb  = (u16*)((char*)d_ws + P_OFF);
        u16* Qb  = (u16*)((char*)d_ws + Q_OFF);

        zero_stats<<<1, 256, 0, stream>>>(stats);
        prep_pack2<<<48, 256, 0, stream>>>(Wfull, Wsk, wpq, w3t, wskf);
        pq_kernel<<<(N_ATOM + 63) / 64, 256, 0, stream>>>(atom_in, wpq, Pb, Qb);
        estage5<1><<<GRID_E, 512, 0, stream>>>(nbr_fea, nbr_idx, w3t, Pb, Qb, stats, out);
        finalize1<<<1, 256, 0, stream>>>(g1, b1, stats);
        estage5<2><<<GRID_E, 512, 0, stream>>>(nbr_fea, nbr_idx, w3t, Pb, Qb, stats, out);
        finalize2<<<1, 128, 0, stream>>>(g2, b2, stats);
        skip_kernel<<<(N_ATOM + BM5 - 1) / BM5, 256, 0, stream>>>(atom_in, wskf, bsk, stats, out);
    } else {
        u16* wf = (u16*)d_ws;
        zero_stats<<<1, 256, 0, stream>>>(stats);
        prep_pack_slow<<<48, 256, 0, stream>>>(Wfull, Wsk, wf, wskf);
        pass_kernel<1><<<GRID_P, TPB, 0, stream>>>(atom_in, nbr_fea, nbr_idx, wf, stats, out);
        finalize1<<<1, 256, 0, stream>>>(g1, b1, stats);
        pass_kernel<2><<<GRID_P, TPB, 0, stream>>>(atom_in, nbr_fea, nbr_idx, wf, stats, out);
        finalize2<<<1, 128, 0, stream>>>(g2, b2, stats);
        skip_kernel<<<(N_ATOM + BM5 - 1) / BM5, 256, 0, stream>>>(atom_in, wskf, bsk, stats, out);
    }
}

// Round 10
// 981.245 us; speedup vs baseline: 1.8371x; 1.0469x over previous
//
#include <hip/hip_runtime.h>
#include <stdint.h>

#define N_ATOM 100000
#define M_NBR 12
#define A_FEA 128
#define E_FEA 64
#define KDIM 320
#define GDIM 256
#define ROWS (N_ATOM*M_NBR)
#define BN_EPS 1e-5f

typedef unsigned short u16;
typedef unsigned int u32;
typedef __attribute__((ext_vector_type(8))) short short8;
typedef __attribute__((ext_vector_type(4))) float f32x4;

// ---- stats slot indices (floats) ----
#define S_BN1SUM 0
#define S_BN1SSQ 256
#define S_S1 512
#define S_T1 768
#define S_BN2SUM 1024
#define S_BN2SSQ 1152
#define S_S2 1280
#define S_T2 1408
#define STATS_F32 1536

// ---- workspace layout ----
#define WPQ_OFF 0
#define W3T_OFF 131072
#define WSK_OFF 163840
#define STATS_OFF 196608
#define P_OFF 202752
#define PQ_BYTES ((size_t)N_ATOM*256*2)            // 51,200,000
#define Q_OFF (P_OFF + PQ_BYTES)
#define NEED_FAST3 (P_OFF + 2*PQ_BYTES)            // ~102.6 MB

__device__ __forceinline__ u16 f2bf(float x) {
    union { float f; u32 u; } v; v.f = x;
    u32 r = v.u + 0x7FFFu + ((v.u >> 16) & 1u);
    return (u16)(r >> 16);
}
__device__ __forceinline__ float bflo(u32 x) { return __uint_as_float(x << 16); }
__device__ __forceinline__ float bfhi(u32 x) { return __uint_as_float(x & 0xFFFF0000u); }
__device__ __forceinline__ float softplus_f(float x) {
    return fmaxf(x, 0.f) + __logf(1.f + __expf(-fabsf(x)));
}
__device__ __forceinline__ float sigmoid_f(float x) {
    return 1.f / (1.f + __expf(-x));
}

// Zero bn accumulators every launch (plain kernel -> always a graph node).
__global__ void zero_stats(float* __restrict__ stats) {
    int t = threadIdx.x;              // 256
    stats[t] = 0.f;
    stats[256 + t] = 0.f;
    stats[1024 + t] = 0.f;
}

__global__ void finalize1(const float* __restrict__ g1, const float* __restrict__ b1,
                          float* __restrict__ stats) {
    int c = threadIdx.x;  // 256
    const float inv_cnt = 1.f / (float)ROWS;
    float mean = stats[S_BN1SUM + c] * inv_cnt;
    float var  = stats[S_BN1SSQ + c] * inv_cnt - mean * mean;
    float iv = rsqrtf(var + BN_EPS);
    float s = g1[c] * iv;
    stats[S_S1 + c] = s;
    stats[S_T1 + c] = fmaf(-mean, s, b1[c]);
}

__global__ void finalize2(const float* __restrict__ g2, const float* __restrict__ b2,
                          float* __restrict__ stats) {
    int c = threadIdx.x;  // 128
    const float inv_cnt = 1.f / (float)N_ATOM;
    float mean = stats[S_BN2SUM + c] * inv_cnt;
    float var  = stats[S_BN2SSQ + c] * inv_cnt - mean * mean;
    float iv = rsqrtf(var + BN_EPS);
    float s = g2[c] * iv;
    stats[S_S2 + c] = s;
    stats[S_T2 + c] = fmaf(-mean, s, b2[c]);
}

// Pack Wpq (B for P/Q GEMM: 128 x 512), W3T (A-frags of W3^T: 256 x 64),
// Wsk (128 x 128) into MFMA fragment order.
__global__ void prep_pack2(const float* __restrict__ Wfull,
                           const float* __restrict__ Wskip,
                           u16* __restrict__ wpq, u16* __restrict__ w3t,
                           u16* __restrict__ wsk) {
    int tid = blockIdx.x * blockDim.x + threadIdx.x;
    int l = tid & 63, fr = l & 15, fq = l >> 4;
    if (tid < 8192) {
        int ct = (tid >> 6) & 31;
        int kt = tid >> 11;                 // 0..3
        int c = ct * 16 + fr;               // 0..511
        int k0 = kt * 32 + fq * 8;          // 0..127
        u16 tmp[8];
        #pragma unroll
        for (int i = 0; i < 8; ++i) {
            int kk = k0 + i;
            float v = (c < 256) ? Wfull[kk * GDIM + c]
                                : Wfull[(128 + kk) * GDIM + (c - 256)];
            tmp[i] = f2bf(v);
        }
        uint4 pk;
        pk.x = (u32)tmp[0] | ((u32)tmp[1] << 16);
        pk.y = (u32)tmp[2] | ((u32)tmp[3] << 16);
        pk.z = (u32)tmp[4] | ((u32)tmp[5] << 16);
        pk.w = (u32)tmp[6] | ((u32)tmp[7] << 16);
        *reinterpret_cast<uint4*>(&wpq[tid * 8]) = pk;
    } else if (tid < 10240) {
        // W3T A-frag: frag=(kt*16+rt16), elem i -> Wfull[256+kt*32+fq*8+i][rt16*16+fr]
        int t2 = tid - 8192;               // 0..2047
        int frag = t2 >> 6;                // 0..31
        int rt16 = frag & 15, kt = frag >> 4;
        int gcol = rt16 * 16 + fr;
        int k0 = kt * 32 + fq * 8;
        u16 tmp[8];
        #pragma unroll
        for (int i = 0; i < 8; ++i) tmp[i] = f2bf(Wfull[(256 + k0 + i) * GDIM + gcol]);
        uint4 pk;
        pk.x = (u32)tmp[0] | ((u32)tmp[1] << 16);
        pk.y = (u32)tmp[2] | ((u32)tmp[3] << 16);
        pk.z = (u32)tmp[4] | ((u32)tmp[5] << 16);
        pk.w = (u32)tmp[6] | ((u32)tmp[7] << 16);
        *reinterpret_cast<uint4*>(&w3t[t2 * 8]) = pk;
    } else if (tid < 12288) {
        int t3 = tid - 10240;
        int ct = (t3 >> 6) & 7;
        int kt = t3 >> 9;                   // 0..3
        int c = ct * 16 + fr;
        int k0 = kt * 32 + fq * 8;
        u16 tmp[8];
        #pragma unroll
        for (int i = 0; i < 8; ++i) tmp[i] = f2bf(Wskip[(k0 + i) * A_FEA + c]);
        uint4 pk;
        pk.x = (u32)tmp[0] | ((u32)tmp[1] << 16);
        pk.y = (u32)tmp[2] | ((u32)tmp[3] << 16);
        pk.z = (u32)tmp[4] | ((u32)tmp[5] << 16);
        pk.w = (u32)tmp[6] | ((u32)tmp[7] << 16);
        *reinterpret_cast<uint4*>(&wsk[t3 * 8]) = pk;
    }
}

// P[n] = atom_in[n] @ Wfull[0:128];  Q[n] = atom_in[n] @ Wfull[128:256]
__launch_bounds__(256)
__global__ void pq_kernel(const float* __restrict__ atom_in,
                          const u16* __restrict__ wpq,
                          u16* __restrict__ Pb, u16* __restrict__ Qb) {
    __shared__ u16 al[64 * 130];
    const int t = threadIdx.x;
    const int w = t >> 6, l = t & 63, fr = l & 15, fq = l >> 4;
    const int n0 = blockIdx.x * 64;

    #pragma unroll
    for (int it = 0; it < 4; ++it) {
        int c = t + it * 256;         // 0..1023
        int row = c >> 4, seg = c & 15;
        int n = n0 + row;
        uint4 pk = {0u, 0u, 0u, 0u};
        if (n < N_ATOM) {
            const float* src = atom_in + (size_t)n * A_FEA + seg * 8;
            float4 x0 = *reinterpret_cast<const float4*>(src);
            float4 x1 = *reinterpret_cast<const float4*>(src + 4);
            pk.x = (u32)f2bf(x0.x) | ((u32)f2bf(x0.y) << 16);
            pk.y = (u32)f2bf(x0.z) | ((u32)f2bf(x0.w) << 16);
            pk.z = (u32)f2bf(x1.x) | ((u32)f2bf(x1.y) << 16);
            pk.w = (u32)f2bf(x1.z) | ((u32)f2bf(x1.w) << 16);
        }
        *reinterpret_cast<uint4*>(&al[row * 130 + seg * 8]) = pk;
    }
    __syncthreads();

    f32x4 acc[4][8];
    #pragma unroll
    for (int rt = 0; rt < 4; ++rt)
        #pragma unroll
        for (int p = 0; p < 8; ++p)
            acc[rt][p] = (f32x4){0.f,0.f,0.f,0.f};

    for (int kt = 0; kt < 4; ++kt) {
        short8 af[4], bf[8];
        #pragma unroll
        for (int rt = 0; rt < 4; ++rt)
            af[rt] = *reinterpret_cast<const short8*>(
                &al[(rt * 16 + fr) * 130 + kt * 32 + fq * 8]);
        #pragma unroll
        for (int p = 0; p < 8; ++p)
            bf[p] = *reinterpret_cast<const short8*>(
                &wpq[((kt * 32 + w * 8 + p) * 64 + l) * 8]);
        #pragma unroll
        for (int rt = 0; rt < 4; ++rt)
            #pragma unroll
            for (int p = 0; p < 8; ++p)
                acc[rt][p] = __builtin_amdgcn_mfma_f32_16x16x32_bf16(
                    af[rt], bf[p], acc[rt][p], 0, 0, 0);
    }

    #pragma unroll
    for (int p = 0; p < 8; ++p) {
        int col = w * 128 + p * 16 + fr;            // 0..511
        u16* dst = (col < 256) ? Pb : Qb;
        int cc = (col < 256) ? col : (col - 256);
        #pragma unroll
        for (int rt = 0; rt < 4; ++rt)
            #pragma unroll
            for (int j = 0; j < 4; ++j) {
                int n = n0 + rt * 16 + fq * 4 + j;
                if (n < N_ATOM) dst[(size_t)n * 256 + cc] = f2bf(acc[rt][p][j]);
            }
    }
}

// =====================================================================
// Edge kernel v6: transposed MFMA; Q gathered DIRECTLY into registers
// (12 x 8B independent loads, issued before the MFMA phase); only nbr
// tile + P rows + 96 idx ints staged in LDS. MODE2's act buffer overlays
// the staging region (all staged data consumed before act is written).
// MODE1 LDS 17.3KB (-> 4 blocks/CU), MODE2 LDS 50.7KB (-> 3 blocks/CU).
// =====================================================================
#define NTILES_E (ROWS/96)     // 12500
#define GRID_E 2500
#define EPAD 66                // u16 stride of nbr tile rows
#define PPAD2 264              // u16 stride of P rows
#define ACT2 132               // f32 stride of act rows
#define E_SH6 (96*EPAD*2)              // 12672
#define P_SH6 E_SH6                    // p at 12672 (8*264*2 = 4224 B)
#define I_SH6 (E_SH6 + 8*PPAD2*2)      // idx at 16896 (384 B) -> 17280
#define SH6_M1 17280
#define SH6_M2 (96*ACT2*4)             // 50688 (act overlays everything)

template<int MODE>
__launch_bounds__(512, 2)
__global__ void estage6(const float* __restrict__ nbr_fea,
                        const int* __restrict__ nbr_idx,
                        const u16* __restrict__ w3t,
                        const u16* __restrict__ Pb,
                        const u16* __restrict__ Qb,
                        float* __restrict__ stats,
                        float* __restrict__ out_ns) {
    constexpr int SHB = (MODE == 1) ? SH6_M1 : SH6_M2;
    __shared__ __align__(16) unsigned char shraw[SHB];
    u16* e_lds = (u16*)shraw;
    u16* p_lds = (u16*)(shraw + P_SH6);
    int* idx_lds = (int*)(shraw + I_SH6);
    float* act = (float*)shraw;          // MODE2 overlay (post-consume)
    float* red = (float*)shraw;          // end-of-kernel reduction scratch

    const int t = threadIdx.x;
    const int w = t >> 6, l = t & 63, fr = l & 15, fq = l >> 4;
    const int gbase0 = w * 16 + fq * 4;        // filter col base (rt=0); core = +128

    // Tile-invariant W3^T A-fragments.
    short8 aw[2][2];
    #pragma unroll
    for (int kt = 0; kt < 2; ++kt)
        #pragma unroll
        for (int rt = 0; rt < 2; ++rt)
            aw[kt][rt] = *reinterpret_cast<const short8*>(
                &w3t[(((kt * 16) + w + rt * 8) * 64 + l) * 8]);

    float s1v[2][4], t1v[2][4];
    if (MODE == 2) {
        #pragma unroll
        for (int rt = 0; rt < 2; ++rt)
            #pragma unroll
            for (int j = 0; j < 4; ++j) {
                int col = gbase0 + rt * 128 + j;
                s1v[rt][j] = stats[S_S1 + col];
                t1v[rt][j] = stats[S_T1 + col];
            }
    }
    float ls[2][4] = {{0,0,0,0},{0,0,0,0}}, lq[2][4] = {{0,0,0,0},{0,0,0,0}};
    float bsum = 0.f, bssq = 0.f;

    for (int tile = blockIdx.x; tile < NTILES_E; tile += GRID_E) {
        const int r0 = tile * 96;
        const int n0a = tile * 8;

        __syncthreads();   // previous-iteration readers done (e/p/idx or act)

        // ---- stage nbr tile: 96 x 64 f32 -> bf16 ----
        #pragma unroll
        for (int i = 0; i < 2; ++i) {
            int o = t + i * 512;
            if (o < 768) {
                int row = o >> 3, seg = o & 7;
                const float* src = nbr_fea + (size_t)(r0 + row) * E_FEA + seg * 8;
                float4 x0 = *reinterpret_cast<const float4*>(src);
                float4 x1 = *reinterpret_cast<const float4*>(src + 4);
                uint4 pk;
                pk.x = (u32)f2bf(x0.x) | ((u32)f2bf(x0.y) << 16);
                pk.y = (u32)f2bf(x0.z) | ((u32)f2bf(x0.w) << 16);
                pk.z = (u32)f2bf(x1.x) | ((u32)f2bf(x1.y) << 16);
                pk.w = (u32)f2bf(x1.z) | ((u32)f2bf(x1.w) << 16);
                *reinterpret_cast<uint4*>(&e_lds[row * EPAD + seg * 8]) = pk;
            }
        }
        // ---- stage P rows (8 x 256 bf16) and idx (96 ints) ----
        if (t < 256) {
            int row = t >> 5, seg = t & 31;
            *reinterpret_cast<uint4*>(&p_lds[row * PPAD2 + seg * 8]) =
                *reinterpret_cast<const uint4*>(&Pb[(size_t)(n0a + row) * 256 + seg * 8]);
        } else if (t >= 416) {
            int e = t - 416;   // 0..95
            idx_lds[e] = nbr_idx[r0 + e];
        }
        __syncthreads();

        // ---- gather Q fragments straight to registers (L3-resident Q);
        //      issued before MFMA so latency hides under compute ----
        uint2 qv0r[6], qv1r[6];
        #pragma unroll
        for (int ct = 0; ct < 6; ++ct) {
            int edge = ct * 16 + fr;
            int jr = idx_lds[edge];
            const u16* qb = Qb + (size_t)jr * 256;
            qv0r[ct] = *reinterpret_cast<const uint2*>(qb + gbase0);
            qv1r[ct] = *reinterpret_cast<const uint2*>(qb + gbase0 + 128);
        }

        // ---- MFMA: gated^T tile, acc[rt][ct] ----
        f32x4 acc[2][6];
        #pragma unroll
        for (int rt = 0; rt < 2; ++rt)
            #pragma unroll
            for (int ct = 0; ct < 6; ++ct)
                acc[rt][ct] = (f32x4){0.f,0.f,0.f,0.f};
        #pragma unroll
        for (int kt = 0; kt < 2; ++kt) {
            short8 bf[6];
            #pragma unroll
            for (int ct = 0; ct < 6; ++ct)
                bf[ct] = *reinterpret_cast<const short8*>(
                    &e_lds[(ct * 16 + fr) * EPAD + kt * 32 + fq * 8]);
            #pragma unroll
            for (int rt = 0; rt < 2; ++rt)
                #pragma unroll
                for (int ct = 0; ct < 6; ++ct)
                    acc[rt][ct] = __builtin_amdgcn_mfma_f32_16x16x32_bf16(
                        aw[kt][rt], bf[ct], acc[rt][ct], 0, 0, 0);
        }

        if (MODE == 1) {
            #pragma unroll
            for (int ct = 0; ct < 6; ++ct) {
                int edge = ct * 16 + fr;
                int atom = (edge * 171) >> 11;     // edge/12
                uint2 qv0 = qv0r[ct], qv1 = qv1r[ct];
                uint2 pv0 = *reinterpret_cast<const uint2*>(&p_lds[atom * PPAD2 + gbase0]);
                uint2 pv1 = *reinterpret_cast<const uint2*>(&p_lds[atom * PPAD2 + gbase0 + 128]);
                float g;
                g = acc[0][ct][0] + bflo(qv0.x) + bflo(pv0.x); ls[0][0] += g; lq[0][0] = fmaf(g,g,lq[0][0]);
                g = acc[0][ct][1] + bfhi(qv0.x) + bfhi(pv0.x); ls[0][1] += g; lq[0][1] = fmaf(g,g,lq[0][1]);
                g = acc[0][ct][2] + bflo(qv0.y) + bflo(pv0.y); ls[0][2] += g; lq[0][2] = fmaf(g,g,lq[0][2]);
                g = acc[0][ct][3] + bfhi(qv0.y) + bfhi(pv0.y); ls[0][3] += g; lq[0][3] = fmaf(g,g,lq[0][3]);
                g = acc[1][ct][0] + bflo(qv1.x) + bflo(pv1.x); ls[1][0] += g; lq[1][0] = fmaf(g,g,lq[1][0]);
                g = acc[1][ct][1] + bfhi(qv1.x) + bfhi(pv1.x); ls[1][1] += g; lq[1][1] = fmaf(g,g,lq[1][1]);
                g = acc[1][ct][2] + bflo(qv1.y) + bflo(pv1.y); ls[1][2] += g; lq[1][2] = fmaf(g,g,lq[1][2]);
                g = acc[1][ct][3] + bfhi(qv1.y) + bfhi(pv1.y); ls[1][3] += g; lq[1][3] = fmaf(g,g,lq[1][3]);
            }
        } else {
            float ar[6][4];
            #pragma unroll
            for (int ct = 0; ct < 6; ++ct) {
                int edge = ct * 16 + fr;
                int atom = (edge * 171) >> 11;
                uint2 qv0 = qv0r[ct], qv1 = qv1r[ct];
                uint2 pv0 = *reinterpret_cast<const uint2*>(&p_lds[atom * PPAD2 + gbase0]);
                uint2 pv1 = *reinterpret_cast<const uint2*>(&p_lds[atom * PPAD2 + gbase0 + 128]);
                float gf, gc;
                gf = acc[0][ct][0] + bflo(qv0.x) + bflo(pv0.x);
                gc = acc[1][ct][0] + bflo(qv1.x) + bflo(pv1.x);
                ar[ct][0] = sigmoid_f(fmaf(gf, s1v[0][0], t1v[0][0])) * softplus_f(fmaf(gc, s1v[1][0], t1v[1][0]));
                gf = acc[0][ct][1] + bfhi(qv0.x) + bfhi(pv0.x);
                gc = acc[1][ct][1] + bfhi(qv1.x) + bfhi(pv1.x);
                ar[ct][1] = sigmoid_f(fmaf(gf, s1v[0][1], t1v[0][1])) * softplus_f(fmaf(gc, s1v[1][1], t1v[1][1]));
                gf = acc[0][ct][2] + bflo(qv0.y) + bflo(pv0.y);
                gc = acc[1][ct][2] + bflo(qv1.y) + bflo(pv1.y);
                ar[ct][2] = sigmoid_f(fmaf(gf, s1v[0][2], t1v[0][2])) * softplus_f(fmaf(gc, s1v[1][2], t1v[1][2]));
                gf = acc[0][ct][3] + bfhi(qv0.y) + bfhi(pv0.y);
                gc = acc[1][ct][3] + bfhi(qv1.y) + bfhi(pv1.y);
                ar[ct][3] = sigmoid_f(fmaf(gf, s1v[0][3], t1v[0][3])) * softplus_f(fmaf(gc, s1v[1][3], t1v[1][3]));
            }
            __syncthreads();   // e/p/idx fully consumed; act overlays them
            #pragma unroll
            for (int ct = 0; ct < 6; ++ct) {
                int edge = ct * 16 + fr;
                float4 f4 = make_float4(ar[ct][0], ar[ct][1], ar[ct][2], ar[ct][3]);
                *reinterpret_cast<float4*>(&act[edge * ACT2 + gbase0]) = f4;
            }
            __syncthreads();
            // m-sum -> nbr_sumed -> out; bn2 stats
            #pragma unroll
            for (int i = 0; i < 2; ++i) {
                int o = i * 512 + t;
                int a = o >> 7;            // atom 0..7
                int c = t & 127;
                float S = 0.f;
                #pragma unroll
                for (int mm = 0; mm < 12; ++mm)
                    S += act[(a * 12 + mm) * ACT2 + c];
                out_ns[(size_t)(n0a + a) * A_FEA + c] = S;
                bsum += S;
                bssq = fmaf(S, S, bssq);
            }
        }
    }

    if (MODE == 1) {
        #pragma unroll
        for (int rt = 0; rt < 2; ++rt)
            #pragma unroll
            for (int j = 0; j < 4; ++j) {
                float s = ls[rt][j], q = lq[rt][j];
                s += __shfl_xor(s, 1, 64);  s += __shfl_xor(s, 2, 64);
                s += __shfl_xor(s, 4, 64);  s += __shfl_xor(s, 8, 64);
                q += __shfl_xor(q, 1, 64);  q += __shfl_xor(q, 2, 64);
                q += __shfl_xor(q, 4, 64);  q += __shfl_xor(q, 8, 64);
                if (fr == 0) {
                    int col = gbase0 + rt * 128 + j;
                    atomicAdd(&stats[S_BN1SUM + col], s);
                    atomicAdd(&stats[S_BN1SSQ + col], q);
                }
            }
    } else {
        __syncthreads();
        if (t >= 128) {
            red[(t - 128) * 2]     = bsum;
            red[(t - 128) * 2 + 1] = bssq;
        }
        __syncthreads();
        if (t < 128) {
            bsum += red[t * 2]     + red[(128 + t) * 2]     + red[(256 + t) * 2];
            bssq += red[t * 2 + 1] + red[(128 + t) * 2 + 1] + red[(256 + t) * 2 + 1];
            atomicAdd(&stats[S_BN2SUM + t], bsum);
            atomicAdd(&stats[S_BN2SSQ + t], bssq);
        }
    }
}

// Skip GEMM + bn2 affine + softplus (in place on out).
#define BM5 64
__launch_bounds__(256, 2)
__global__ void skip_kernel(const float* __restrict__ atom_in,
                            const u16* __restrict__ wsf,
                            const float* __restrict__ b_skip,
                            const float* __restrict__ stats,
                            float* __restrict__ out) {
    __shared__ u16 a5[BM5 * 136];
    const int t = threadIdx.x;
    const int w = t >> 6, l = t & 63, fr = l & 15, fq = l >> 4;
    const int n0 = blockIdx.x * BM5;

    #pragma unroll
    for (int it = 0; it < 4; ++it) {
        int c = t + it * 256;
        int row = c >> 4, seg = c & 15;
        int n = n0 + row;
        uint4 pk = {0u, 0u, 0u, 0u};
        if (n < N_ATOM) {
            const float* src = atom_in + (size_t)n * A_FEA + seg * 8;
            float4 x0 = *reinterpret_cast<const float4*>(src);
            float4 x1 = *reinterpret_cast<const float4*>(src + 4);
            pk.x = (u32)f2bf(x0.x) | ((u32)f2bf(x0.y) << 16);
            pk.y = (u32)f2bf(x0.z) | ((u32)f2bf(x0.w) << 16);
            pk.z = (u32)f2bf(x1.x) | ((u32)f2bf(x1.y) << 16);
            pk.w = (u32)f2bf(x1.z) | ((u32)f2bf(x1.w) << 16);
        }
        *reinterpret_cast<uint4*>(&a5[row * 136 + seg * 8]) = pk;
    }
    __syncthreads();

    f32x4 acc[4][2];
    #pragma unroll
    for (int rt = 0; rt < 4; ++rt) {
        acc[rt][0] = (f32x4){0.f,0.f,0.f,0.f};
        acc[rt][1] = (f32x4){0.f,0.f,0.f,0.f};
    }
    for (int kt = 0; kt < 4; ++kt) {
        short8 af[4], bf[2];
        #pragma unroll
        for (int rt = 0; rt < 4; ++rt)
            af[rt] = *reinterpret_cast<const short8*>(
                &a5[(rt * 16 + fr) * 136 + kt * 32 + fq * 8]);
        #pragma unroll
        for (int p = 0; p < 2; ++p)
            bf[p] = *reinterpret_cast<const short8*>(
                &wsf[((kt * 8 + 2 * w + p) * 64 + l) * 8]);
        #pragma unroll
        for (int rt = 0; rt < 4; ++rt)
            #pragma unroll
            for (int p = 0; p < 2; ++p)
                acc[rt][p] = __builtin_amdgcn_mfma_f32_16x16x32_bf16(
                    af[rt], bf[p], acc[rt][p], 0, 0, 0);
    }

    #pragma unroll
    for (int p = 0; p < 2; ++p) {
        int col = w * 32 + p * 16 + fr;
        float bs = b_skip[col];
        float s2 = stats[S_S2 + col];
        float t2 = stats[S_T2 + col];
        #pragma unroll
        for (int rt = 0; rt < 4; ++rt)
            #pragma unroll
            for (int j = 0; j < 4; ++j) {
                int n = n0 + rt * 16 + fq * 4 + j;
                if (n < N_ATOM) {
                    size_t o = (size_t)n * A_FEA + col;
                    float S = out[o];
                    out[o] = softplus_f(acc[rt][p][j] + bs + fmaf(S, s2, t2));
                }
            }
    }
}

// =====================================================================
// SLOW fallback path (round-2 validated code, unchanged)
// =====================================================================
#define BM 96
#define NTILES (ROWS/BM)
#define GRID_P 2500
#define TPB 256
#define APAD 328
#define ACTPAD 132

__global__ void prep_pack_slow(const float* __restrict__ Wfull,
                               const float* __restrict__ Wskip,
                               u16* __restrict__ wf, u16* __restrict__ wsf) {
    int tid = blockIdx.x * blockDim.x + threadIdx.x;
    if (tid < 10240) {
        int l = tid & 63;
        int ct = (tid >> 6) & 15;
        int kt = tid >> 10;
        int fr = l & 15, fq = l >> 4;
        int col = ct * 16 + fr;
        int k0 = kt * 32 + fq * 8;
        u16 tmp[8];
        #pragma unroll
        for (int i = 0; i < 8; ++i) tmp[i] = f2bf(Wfull[(k0 + i) * GDIM + col]);
        uint4 pk;
        pk.x = (u32)tmp[0] | ((u32)tmp[1] << 16);
        pk.y = (u32)tmp[2] | ((u32)tmp[3] << 16);
        pk.z = (u32)tmp[4] | ((u32)tmp[5] << 16);
        pk.w = (u32)tmp[6] | ((u32)tmp[7] << 16);
        *reinterpret_cast<uint4*>(&wf[tid * 8]) = pk;
    } else if (tid < 12288) {
        int t2 = tid - 10240;
        int l = t2 & 63;
        int ct = (t2 >> 6) & 7;
        int kt = t2 >> 9;
        int fr = l & 15, fq = l >> 4;
        int col = ct * 16 + fr;
        int k0 = kt * 32 + fq * 8;
        u16 tmp[8];
        #pragma unroll
        for (int i = 0; i < 8; ++i) tmp[i] = f2bf(Wskip[(k0 + i) * A_FEA + col]);
        uint4 pk;
        pk.x = (u32)tmp[0] | ((u32)tmp[1] << 16);
        pk.y = (u32)tmp[2] | ((u32)tmp[3] << 16);
        pk.z = (u32)tmp[4] | ((u32)tmp[5] << 16);
        pk.w = (u32)tmp[6] | ((u32)tmp[7] << 16);
        *reinterpret_cast<uint4*>(&wsf[t2 * 8]) = pk;
    }
}

template<int PASS>
__launch_bounds__(TPB, 2)
__global__ void pass_kernel(const float* __restrict__ atom_in,
                            const float* __restrict__ nbr_fea,
                            const int* __restrict__ nbr_idx,
                            const u16* __restrict__ wf,
                            float* __restrict__ stats,
                            float* __restrict__ out_ns) {
    __shared__ union {
        u16 a[BM * APAD];
        float act[BM * ACTPAD];
    } sh;

    const int t = threadIdx.x;
    const int w = t >> 6, l = t & 63, fr = l & 15, fq = l >> 4;
    const int ct0 = 2 * w;

    int colp[4];
    colp[0] = ct0 * 16 + fr;
    colp[1] = colp[0] + 16;
    colp[2] = colp[0] + 128;
    colp[3] = colp[1] + 128;

    float s1v[4], t1v[4];
    if (PASS == 2) {
        #pragma unroll
        for (int p = 0; p < 4; ++p) {
            s1v[p] = stats[S_S1 + colp[p]];
            t1v[p] = stats[S_T1 + colp[p]];
        }
    }
    float ls[4] = {0.f,0.f,0.f,0.f}, lq[4] = {0.f,0.f,0.f,0.f};
    float bsum = 0.f, bssq = 0.f;

    for (int tile = blockIdx.x; tile < NTILES; tile += GRID_P) {
        const int n0 = tile * 8;

        __syncthreads();
        for (int it = 0; it < 15; ++it) {
            int c = t + it * TPB;
            int row = c / 40;
            int seg = c - row * 40;
            int an = row / 12;
            int m  = row - an * 12;
            int na = n0 + an;
            const float* src;
            if (seg < 16) {
                src = atom_in + (size_t)na * A_FEA + seg * 8;
            } else if (seg < 32) {
                int j = nbr_idx[na * M_NBR + m];
                src = atom_in + (size_t)j * A_FEA + (seg - 16) * 8;
            } else {
                src = nbr_fea + ((size_t)na * M_NBR + m) * E_FEA + (seg - 32) * 8;
            }
            float4 x0 = *reinterpret_cast<const float4*>(src);
            float4 x1 = *reinterpret_cast<const float4*>(src + 4);
            uint4 pk;
            pk.x = (u32)f2bf(x0.x) | ((u32)f2bf(x0.y) << 16);
            pk.y = (u32)f2bf(x0.z) | ((u32)f2bf(x0.w) << 16);
            pk.z = (u32)f2bf(x1.x) | ((u32)f2bf(x1.y) << 16);
            pk.w = (u32)f2bf(x1.z) | ((u32)f2bf(x1.w) << 16);
            *reinterpret_cast<uint4*>(&sh.a[row * APAD + seg * 8]) = pk;
        }
        __syncthreads();

        f32x4 acc[6][4];
        #pragma unroll
        for (int rt = 0; rt < 6; ++rt)
            #pragma unroll
            for (int p = 0; p < 4; ++p)
                acc[rt][p] = (f32x4){0.f,0.f,0.f,0.f};

        for (int kt = 0; kt < 10; ++kt) {
            short8 af[6], bf[4];
            #pragma unroll
            for (int rt = 0; rt < 6; ++rt)
                af[rt] = *reinterpret_cast<const short8*>(
                    &sh.a[(rt * 16 + fr) * APAD + kt * 32 + fq * 8]);
            #pragma unroll
            for (int p = 0; p < 4; ++p) {
                int ct = (p < 2) ? (ct0 + p) : (ct0 + 8 + (p - 2));
                bf[p] = *reinterpret_cast<const short8*>(
                    &wf[((kt * 16 + ct) * 64 + l) * 8]);
            }
            #pragma unroll
            for (int rt = 0; rt < 6; ++rt)
                #pragma unroll
                for (int p = 0; p < 4; ++p)
                    acc[rt][p] = __builtin_amdgcn_mfma_f32_16x16x32_bf16(
                        af[rt], bf[p], acc[rt][p], 0, 0, 0);
        }

        if (PASS == 1) {
            #pragma unroll
            for (int p = 0; p < 4; ++p)
                #pragma unroll
                for (int rt = 0; rt < 6; ++rt)
                    #pragma unroll
                    for (int j = 0; j < 4; ++j) {
                        float v = acc[rt][p][j];
                        ls[p] += v;
                        lq[p] = fmaf(v, v, lq[p]);
                    }
        } else {
            __syncthreads();
            #pragma unroll
            for (int rt = 0; rt < 6; ++rt)
                #pragma unroll
                for (int p = 0; p < 2; ++p)
                    #pragma unroll
                    for (int j = 0; j < 4; ++j) {
                        float gf = fmaf(acc[rt][p][j],     s1v[p],     t1v[p]);
                        float gc = fmaf(acc[rt][2 + p][j], s1v[2 + p], t1v[2 + p]);
                        float a = sigmoid_f(gf) * softplus_f(gc);
                        int row = rt * 16 + fq * 4 + j;
                        int colact = ct0 * 16 + p * 16 + fr;
                        sh.act[row * ACTPAD + colact] = a;
                    }
            __syncthreads();
            #pragma unroll
            for (int i = 0; i < 4; ++i) {
                int o = i * TPB + t;
                int a = o >> 7;
                int c = o & 127;
                float S = 0.f;
                #pragma unroll
                for (int mm = 0; mm < 12; ++mm)
                    S += sh.act[(a * 12 + mm) * ACTPAD + c];
                out_ns[(size_t)(n0 + a) * A_FEA + c] = S;
                bsum += S;
                bssq = fmaf(S, S, bssq);
            }
        }
    }

    if (PASS == 1) {
        #pragma unroll
        for (int p = 0; p < 4; ++p) {
            float s = ls[p], q = lq[p];
            s += __shfl_xor(s, 16, 64);
            s += __shfl_xor(s, 32, 64);
            q += __shfl_xor(q, 16, 64);
            q += __shfl_xor(q, 32, 64);
            if (fq == 0) {
                atomicAdd(&stats[S_BN1SUM + colp[p]], s);
                atomicAdd(&stats[S_BN1SSQ + colp[p]], q);
            }
        }
    } else {
        __syncthreads();
        if (t >= 128) {
            sh.act[(t - 128) * 2]     = bsum;
            sh.act[(t - 128) * 2 + 1] = bssq;
        }
        __syncthreads();
        if (t < 128) {
            bsum += sh.act[t * 2];
            bssq += sh.act[t * 2 + 1];
            atomicAdd(&stats[S_BN2SUM + t], bsum);
            atomicAdd(&stats[S_BN2SSQ + t], bssq);
        }
    }
}

// =====================================================================
extern "C" void kernel_launch(void* const* d_in, const int* in_sizes, int n_in,
                              void* d_out, int out_size, void* d_ws, size_t ws_size,
                              hipStream_t stream) {
    (void)in_sizes; (void)n_in; (void)out_size;
    const float* atom_in = (const float*)d_in[0];
    const float* nbr_fea = (const float*)d_in[1];
    const int*   nbr_idx = (const int*)d_in[2];
    const float* Wfull   = (const float*)d_in[3];
    // d_in[4] = b_full: cancels exactly under batchnorm1 -> unused
    const float* g1      = (const float*)d_in[5];
    const float* b1      = (const float*)d_in[6];
    const float* g2      = (const float*)d_in[7];
    const float* b2      = (const float*)d_in[8];
    const float* Wsk     = (const float*)d_in[9];
    const float* bsk     = (const float*)d_in[10];
    float* out = (float*)d_out;

    float* stats = (float*)((char*)d_ws + STATS_OFF);
    u16* wskf = (u16*)((char*)d_ws + WSK_OFF);

    if (ws_size >= NEED_FAST3) {
        u16* wpq = (u16*)d_ws;
        u16* w3t = (u16*)((char*)d_ws + W3T_OFF);
        u16* Pb  = (u16*)((char*)d_ws + P_OFF);
        u16* Qb  = (u16*)((char*)d_ws + Q_OFF);

        zero_stats<<<1, 256, 0, stream>>>(stats);
        prep_pack2<<<48, 256, 0, stream>>>(Wfull, Wsk, wpq, w3t, wskf);
        pq_kernel<<<(N_ATOM + 63) / 64, 256, 0, stream>>>(atom_in, wpq, Pb, Qb);
        estage6<1><<<GRID_E, 512, 0, stream>>>(nbr_fea, nbr_idx, w3t, Pb, Qb, stats, out);
        finalize1<<<1, 256, 0, stream>>>(g1, b1, stats);
        estage6<2><<<GRID_E, 512, 0, stream>>>(nbr_fea, nbr_idx, w3t, Pb, Qb, stats, out);
        finalize2<<<1, 128, 0, stream>>>(g2, b2, stats);
        skip_kernel<<<(N_ATOM + BM5 - 1) / BM5, 256, 0, stream>>>(atom_in, wskf, bsk, stats, out);
    } else {
        u16* wf = (u16*)d_ws;
        zero_stats<<<1, 256, 0, stream>>>(stats);
        prep_pack_slow<<<48, 256, 0, stream>>>(Wfull, Wsk, wf, wskf);
        pass_kernel<1><<<GRID_P, TPB, 0, stream>>>(atom_in, nbr_fea, nbr_idx, wf, stats, out);
        finalize1<<<1, 256, 0, stream>>>(g1, b1, stats);
        pass_kernel<2><<<GRID_P, TPB, 0, stream>>>(atom_in, nbr_fea, nbr_idx, wf, stats, out);
        finalize2<<<1, 128, 0, stream>>>(g2, b2, stats);
        skip_kernel<<<(N_ATOM + BM5 - 1) / BM5, 256, 0, stream>>>(atom_in, wskf, bsk, stats, out);
    }
}

// Round 11
// 841.379 us; speedup vs baseline: 2.1425x; 1.1662x over previous
//
#include <hip/hip_runtime.h>
#include <stdint.h>

#define N_ATOM 100000
#define M_NBR 12
#define A_FEA 128
#define E_FEA 64
#define KDIM 320
#define GDIM 256
#define ROWS (N_ATOM*M_NBR)
#define BN_EPS 1e-5f

typedef unsigned short u16;
typedef unsigned int u32;
typedef __attribute__((ext_vector_type(8))) short short8;
typedef __attribute__((ext_vector_type(4))) float f32x4;

// ---- stats slot indices (floats) ----
#define S_BN1SUM 0
#define S_BN1SSQ 256
#define S_S1 512
#define S_T1 768
#define S_BN2SUM 1024
#define S_BN2SSQ 1152
#define S_S2 1280
#define S_T2 1408
#define STATS_F32 1536

// ---- workspace layout ----
#define WPQ_OFF 0
#define W3T_OFF 131072
#define WSK_OFF 163840
#define STATS_OFF 196608
#define P_OFF 202752
#define PQ_BYTES ((size_t)N_ATOM*256*2)            // 51,200,000
#define Q_OFF (P_OFF + PQ_BYTES)
#define NEED_FAST3 (P_OFF + 2*PQ_BYTES)            // ~102.6 MB (MID)
#define GATED_OFF NEED_FAST3                       // 102,602,752
#define GATED_BYTES ((size_t)ROWS*256*2)           // 614,400,000
#define NEED_FASTW (GATED_OFF + GATED_BYTES)       // ~717 MB (proven available in R3)

__device__ __forceinline__ u16 f2bf(float x) {
    union { float f; u32 u; } v; v.f = x;
    u32 r = v.u + 0x7FFFu + ((v.u >> 16) & 1u);
    return (u16)(r >> 16);
}
__device__ __forceinline__ float bflo(u32 x) { return __uint_as_float(x << 16); }
__device__ __forceinline__ float bfhi(u32 x) { return __uint_as_float(x & 0xFFFF0000u); }
__device__ __forceinline__ float softplus_f(float x) {
    return fmaxf(x, 0.f) + __logf(1.f + __expf(-fabsf(x)));
}
__device__ __forceinline__ float sigmoid_f(float x) {
    return 1.f / (1.f + __expf(-x));
}

// Zero bn accumulators every launch (plain kernel -> always a graph node).
__global__ void zero_stats(float* __restrict__ stats) {
    int t = threadIdx.x;              // 256
    stats[t] = 0.f;
    stats[256 + t] = 0.f;
    stats[1024 + t] = 0.f;
}

__global__ void finalize1(const float* __restrict__ g1, const float* __restrict__ b1,
                          float* __restrict__ stats) {
    int c = threadIdx.x;  // 256
    const float inv_cnt = 1.f / (float)ROWS;
    float mean = stats[S_BN1SUM + c] * inv_cnt;
    float var  = stats[S_BN1SSQ + c] * inv_cnt - mean * mean;
    float iv = rsqrtf(var + BN_EPS);
    float s = g1[c] * iv;
    stats[S_S1 + c] = s;
    stats[S_T1 + c] = fmaf(-mean, s, b1[c]);
}

__global__ void finalize2(const float* __restrict__ g2, const float* __restrict__ b2,
                          float* __restrict__ stats) {
    int c = threadIdx.x;  // 128
    const float inv_cnt = 1.f / (float)N_ATOM;
    float mean = stats[S_BN2SUM + c] * inv_cnt;
    float var  = stats[S_BN2SSQ + c] * inv_cnt - mean * mean;
    float iv = rsqrtf(var + BN_EPS);
    float s = g2[c] * iv;
    stats[S_S2 + c] = s;
    stats[S_T2 + c] = fmaf(-mean, s, b2[c]);
}

// Pack Wpq (B for P/Q GEMM: 128 x 512), W3T (A-frags of W3^T: 256 x 64),
// Wsk (128 x 128) into MFMA fragment order.
__global__ void prep_pack2(const float* __restrict__ Wfull,
                           const float* __restrict__ Wskip,
                           u16* __restrict__ wpq, u16* __restrict__ w3t,
                           u16* __restrict__ wsk) {
    int tid = blockIdx.x * blockDim.x + threadIdx.x;
    int l = tid & 63, fr = l & 15, fq = l >> 4;
    if (tid < 8192) {
        int ct = (tid >> 6) & 31;
        int kt = tid >> 11;                 // 0..3
        int c = ct * 16 + fr;               // 0..511
        int k0 = kt * 32 + fq * 8;          // 0..127
        u16 tmp[8];
        #pragma unroll
        for (int i = 0; i < 8; ++i) {
            int kk = k0 + i;
            float v = (c < 256) ? Wfull[kk * GDIM + c]
                                : Wfull[(128 + kk) * GDIM + (c - 256)];
            tmp[i] = f2bf(v);
        }
        uint4 pk;
        pk.x = (u32)tmp[0] | ((u32)tmp[1] << 16);
        pk.y = (u32)tmp[2] | ((u32)tmp[3] << 16);
        pk.z = (u32)tmp[4] | ((u32)tmp[5] << 16);
        pk.w = (u32)tmp[6] | ((u32)tmp[7] << 16);
        *reinterpret_cast<uint4*>(&wpq[tid * 8]) = pk;
    } else if (tid < 10240) {
        // W3T A-frag: frag=(kt*16+rt16), elem i -> Wfull[256+kt*32+fq*8+i][rt16*16+fr]
        int t2 = tid - 8192;               // 0..2047
        int frag = t2 >> 6;                // 0..31
        int rt16 = frag & 15, kt = frag >> 4;
        int gcol = rt16 * 16 + fr;
        int k0 = kt * 32 + fq * 8;
        u16 tmp[8];
        #pragma unroll
        for (int i = 0; i < 8; ++i) tmp[i] = f2bf(Wfull[(256 + k0 + i) * GDIM + gcol]);
        uint4 pk;
        pk.x = (u32)tmp[0] | ((u32)tmp[1] << 16);
        pk.y = (u32)tmp[2] | ((u32)tmp[3] << 16);
        pk.z = (u32)tmp[4] | ((u32)tmp[5] << 16);
        pk.w = (u32)tmp[6] | ((u32)tmp[7] << 16);
        *reinterpret_cast<uint4*>(&w3t[t2 * 8]) = pk;
    } else if (tid < 12288) {
        int t3 = tid - 10240;
        int ct = (t3 >> 6) & 7;
        int kt = t3 >> 9;                   // 0..3
        int c = ct * 16 + fr;
        int k0 = kt * 32 + fq * 8;
        u16 tmp[8];
        #pragma unroll
        for (int i = 0; i < 8; ++i) tmp[i] = f2bf(Wskip[(k0 + i) * A_FEA + c]);
        uint4 pk;
        pk.x = (u32)tmp[0] | ((u32)tmp[1] << 16);
        pk.y = (u32)tmp[2] | ((u32)tmp[3] << 16);
        pk.z = (u32)tmp[4] | ((u32)tmp[5] << 16);
        pk.w = (u32)tmp[6] | ((u32)tmp[7] << 16);
        *reinterpret_cast<uint4*>(&wsk[t3 * 8]) = pk;
    }
}

// P[n] = atom_in[n] @ Wfull[0:128];  Q[n] = atom_in[n] @ Wfull[128:256]
__launch_bounds__(256)
__global__ void pq_kernel(const float* __restrict__ atom_in,
                          const u16* __restrict__ wpq,
                          u16* __restrict__ Pb, u16* __restrict__ Qb) {
    __shared__ u16 al[64 * 130];
    const int t = threadIdx.x;
    const int w = t >> 6, l = t & 63, fr = l & 15, fq = l >> 4;
    const int n0 = blockIdx.x * 64;

    #pragma unroll
    for (int it = 0; it < 4; ++it) {
        int c = t + it * 256;         // 0..1023
        int row = c >> 4, seg = c & 15;
        int n = n0 + row;
        uint4 pk = {0u, 0u, 0u, 0u};
        if (n < N_ATOM) {
            const float* src = atom_in + (size_t)n * A_FEA + seg * 8;
            float4 x0 = *reinterpret_cast<const float4*>(src);
            float4 x1 = *reinterpret_cast<const float4*>(src + 4);
            pk.x = (u32)f2bf(x0.x) | ((u32)f2bf(x0.y) << 16);
            pk.y = (u32)f2bf(x0.z) | ((u32)f2bf(x0.w) << 16);
            pk.z = (u32)f2bf(x1.x) | ((u32)f2bf(x1.y) << 16);
            pk.w = (u32)f2bf(x1.z) | ((u32)f2bf(x1.w) << 16);
        }
        *reinterpret_cast<uint4*>(&al[row * 130 + seg * 8]) = pk;
    }
    __syncthreads();

    f32x4 acc[4][8];
    #pragma unroll
    for (int rt = 0; rt < 4; ++rt)
        #pragma unroll
        for (int p = 0; p < 8; ++p)
            acc[rt][p] = (f32x4){0.f,0.f,0.f,0.f};

    for (int kt = 0; kt < 4; ++kt) {
        short8 af[4], bf[8];
        #pragma unroll
        for (int rt = 0; rt < 4; ++rt)
            af[rt] = *reinterpret_cast<const short8*>(
                &al[(rt * 16 + fr) * 130 + kt * 32 + fq * 8]);
        #pragma unroll
        for (int p = 0; p < 8; ++p)
            bf[p] = *reinterpret_cast<const short8*>(
                &wpq[((kt * 32 + w * 8 + p) * 64 + l) * 8]);
        #pragma unroll
        for (int rt = 0; rt < 4; ++rt)
            #pragma unroll
            for (int p = 0; p < 8; ++p)
                acc[rt][p] = __builtin_amdgcn_mfma_f32_16x16x32_bf16(
                    af[rt], bf[p], acc[rt][p], 0, 0, 0);
    }

    #pragma unroll
    for (int p = 0; p < 8; ++p) {
        int col = w * 128 + p * 16 + fr;            // 0..511
        u16* dst = (col < 256) ? Pb : Qb;
        int cc = (col < 256) ? col : (col - 256);
        #pragma unroll
        for (int rt = 0; rt < 4; ++rt)
            #pragma unroll
            for (int j = 0; j < 4; ++j) {
                int n = n0 + rt * 16 + fq * 4 + j;
                if (n < N_ATOM) dst[(size_t)n * 256 + cc] = f2bf(acc[rt][p][j]);
            }
    }
}

// =====================================================================
// Edge pass A (single gather pass): transposed MFMA, Q gathered to regs,
// bn1 stats + gated written to ws as bf16 (streaming). LDS 17.3 KB.
// =====================================================================
#define NTILES_E (ROWS/96)     // 12500
#define GRID_E 2500
#define EPAD 66                // u16 stride of nbr tile rows
#define PPAD2 264              // u16 stride of P rows
#define E_SH6 (96*EPAD*2)              // 12672
#define P_SH6 E_SH6                    // p at 12672 (8*264*2 = 4224 B)
#define I_SH6 (E_SH6 + 8*PPAD2*2)      // idx at 16896 (384 B) -> 17280
#define SH7 17280

__launch_bounds__(512, 2)
__global__ void estage7(const float* __restrict__ nbr_fea,
                        const int* __restrict__ nbr_idx,
                        const u16* __restrict__ w3t,
                        const u16* __restrict__ Pb,
                        const u16* __restrict__ Qb,
                        float* __restrict__ stats,
                        u16* __restrict__ gated) {
    __shared__ __align__(16) unsigned char shraw[SH7];
    u16* e_lds = (u16*)shraw;
    u16* p_lds = (u16*)(shraw + P_SH6);
    int* idx_lds = (int*)(shraw + I_SH6);

    const int t = threadIdx.x;
    const int w = t >> 6, l = t & 63, fr = l & 15, fq = l >> 4;
    const int gbase0 = w * 16 + fq * 4;        // filter col base; core = +128

    // Tile-invariant W3^T A-fragments.
    short8 aw[2][2];
    #pragma unroll
    for (int kt = 0; kt < 2; ++kt)
        #pragma unroll
        for (int rt = 0; rt < 2; ++rt)
            aw[kt][rt] = *reinterpret_cast<const short8*>(
                &w3t[(((kt * 16) + w + rt * 8) * 64 + l) * 8]);

    float ls[2][4] = {{0,0,0,0},{0,0,0,0}}, lq[2][4] = {{0,0,0,0},{0,0,0,0}};

    for (int tile = blockIdx.x; tile < NTILES_E; tile += GRID_E) {
        const int r0 = tile * 96;
        const int n0a = tile * 8;

        __syncthreads();   // previous-iteration readers done

        // ---- stage nbr tile: 96 x 64 f32 -> bf16 ----
        #pragma unroll
        for (int i = 0; i < 2; ++i) {
            int o = t + i * 512;
            if (o < 768) {
                int row = o >> 3, seg = o & 7;
                const float* src = nbr_fea + (size_t)(r0 + row) * E_FEA + seg * 8;
                float4 x0 = *reinterpret_cast<const float4*>(src);
                float4 x1 = *reinterpret_cast<const float4*>(src + 4);
                uint4 pk;
                pk.x = (u32)f2bf(x0.x) | ((u32)f2bf(x0.y) << 16);
                pk.y = (u32)f2bf(x0.z) | ((u32)f2bf(x0.w) << 16);
                pk.z = (u32)f2bf(x1.x) | ((u32)f2bf(x1.y) << 16);
                pk.w = (u32)f2bf(x1.z) | ((u32)f2bf(x1.w) << 16);
                *reinterpret_cast<uint4*>(&e_lds[row * EPAD + seg * 8]) = pk;
            }
        }
        // ---- stage P rows (8 x 256 bf16) and idx (96 ints) ----
        if (t < 256) {
            int row = t >> 5, seg = t & 31;
            *reinterpret_cast<uint4*>(&p_lds[row * PPAD2 + seg * 8]) =
                *reinterpret_cast<const uint4*>(&Pb[(size_t)(n0a + row) * 256 + seg * 8]);
        } else if (t >= 416) {
            int e = t - 416;   // 0..95
            idx_lds[e] = nbr_idx[r0 + e];
        }
        __syncthreads();

        // ---- gather Q fragments straight to registers ----
        uint2 qv0r[6], qv1r[6];
        #pragma unroll
        for (int ct = 0; ct < 6; ++ct) {
            int edge = ct * 16 + fr;
            int jr = idx_lds[edge];
            const u16* qb = Qb + (size_t)jr * 256;
            qv0r[ct] = *reinterpret_cast<const uint2*>(qb + gbase0);
            qv1r[ct] = *reinterpret_cast<const uint2*>(qb + gbase0 + 128);
        }

        // ---- MFMA: gated^T tile, acc[rt][ct] ----
        f32x4 acc[2][6];
        #pragma unroll
        for (int rt = 0; rt < 2; ++rt)
            #pragma unroll
            for (int ct = 0; ct < 6; ++ct)
                acc[rt][ct] = (f32x4){0.f,0.f,0.f,0.f};
        #pragma unroll
        for (int kt = 0; kt < 2; ++kt) {
            short8 bf[6];
            #pragma unroll
            for (int ct = 0; ct < 6; ++ct)
                bf[ct] = *reinterpret_cast<const short8*>(
                    &e_lds[(ct * 16 + fr) * EPAD + kt * 32 + fq * 8]);
            #pragma unroll
            for (int rt = 0; rt < 2; ++rt)
                #pragma unroll
                for (int ct = 0; ct < 6; ++ct)
                    acc[rt][ct] = __builtin_amdgcn_mfma_f32_16x16x32_bf16(
                        aw[kt][rt], bf[ct], acc[rt][ct], 0, 0, 0);
        }

        // ---- epilogue: g = R + P + Q; bn1 stats; write gated bf16 ----
        #pragma unroll
        for (int ct = 0; ct < 6; ++ct) {
            int edge = ct * 16 + fr;
            int atom = (edge * 171) >> 11;     // edge/12
            uint2 qv0 = qv0r[ct], qv1 = qv1r[ct];
            uint2 pv0 = *reinterpret_cast<const uint2*>(&p_lds[atom * PPAD2 + gbase0]);
            uint2 pv1 = *reinterpret_cast<const uint2*>(&p_lds[atom * PPAD2 + gbase0 + 128]);
            float g00 = acc[0][ct][0] + bflo(qv0.x) + bflo(pv0.x);
            float g01 = acc[0][ct][1] + bfhi(qv0.x) + bfhi(pv0.x);
            float g02 = acc[0][ct][2] + bflo(qv0.y) + bflo(pv0.y);
            float g03 = acc[0][ct][3] + bfhi(qv0.y) + bfhi(pv0.y);
            float g10 = acc[1][ct][0] + bflo(qv1.x) + bflo(pv1.x);
            float g11 = acc[1][ct][1] + bfhi(qv1.x) + bfhi(pv1.x);
            float g12 = acc[1][ct][2] + bflo(qv1.y) + bflo(pv1.y);
            float g13 = acc[1][ct][3] + bfhi(qv1.y) + bfhi(pv1.y);
            ls[0][0] += g00; lq[0][0] = fmaf(g00,g00,lq[0][0]);
            ls[0][1] += g01; lq[0][1] = fmaf(g01,g01,lq[0][1]);
            ls[0][2] += g02; lq[0][2] = fmaf(g02,g02,lq[0][2]);
            ls[0][3] += g03; lq[0][3] = fmaf(g03,g03,lq[0][3]);
            ls[1][0] += g10; lq[1][0] = fmaf(g10,g10,lq[1][0]);
            ls[1][1] += g11; lq[1][1] = fmaf(g11,g11,lq[1][1]);
            ls[1][2] += g12; lq[1][2] = fmaf(g12,g12,lq[1][2]);
            ls[1][3] += g13; lq[1][3] = fmaf(g13,g13,lq[1][3]);
            size_t grow = (size_t)(r0 + edge) * 256;
            uint2 w0, w1;
            w0.x = (u32)f2bf(g00) | ((u32)f2bf(g01) << 16);
            w0.y = (u32)f2bf(g02) | ((u32)f2bf(g03) << 16);
            w1.x = (u32)f2bf(g10) | ((u32)f2bf(g11) << 16);
            w1.y = (u32)f2bf(g12) | ((u32)f2bf(g13) << 16);
            *reinterpret_cast<uint2*>(&gated[grow + gbase0]) = w0;
            *reinterpret_cast<uint2*>(&gated[grow + gbase0 + 128]) = w1;
        }
    }

    #pragma unroll
    for (int rt = 0; rt < 2; ++rt)
        #pragma unroll
        for (int j = 0; j < 4; ++j) {
            float s = ls[rt][j], q = lq[rt][j];
            s += __shfl_xor(s, 1, 64);  s += __shfl_xor(s, 2, 64);
            s += __shfl_xor(s, 4, 64);  s += __shfl_xor(s, 8, 64);
            q += __shfl_xor(q, 1, 64);  q += __shfl_xor(q, 2, 64);
            q += __shfl_xor(q, 4, 64);  q += __shfl_xor(q, 8, 64);
            if (fr == 0) {
                int col = gbase0 + rt * 128 + j;
                atomicAdd(&stats[S_BN1SUM + col], s);
                atomicAdd(&stats[S_BN1SSQ + col], q);
            }
        }
}

// Streaming pass B (validated in R3): read gated bf16, bn1 affine +
// sigmoid*softplus, m-sum -> out (nbr_sumed), accumulate bn2 stats.
__launch_bounds__(256)
__global__ void apply_kernel(const u16* __restrict__ gated,
                             float* __restrict__ stats,
                             float* __restrict__ out) {
    __shared__ float red[4][64][4];
    const int t = threadIdx.x;
    const int lidc = t & 63, aoff = t >> 6;
    const int c0 = lidc * 2;
    const int n0 = blockIdx.x * 64;

    const float s1f0 = stats[S_S1 + c0],     t1f0 = stats[S_T1 + c0];
    const float s1f1 = stats[S_S1 + c0 + 1], t1f1 = stats[S_T1 + c0 + 1];
    const float s1c0 = stats[S_S1 + 128 + c0],     t1c0 = stats[S_T1 + 128 + c0];
    const float s1c1 = stats[S_S1 + 128 + c0 + 1], t1c1 = stats[S_T1 + 128 + c0 + 1];

    float bs0 = 0.f, bq0 = 0.f, bs1 = 0.f, bq1 = 0.f;

    for (int a = aoff; a < 64; a += 4) {
        int n = n0 + a;
        if (n >= N_ATOM) continue;
        float S0 = 0.f, S1 = 0.f;
        const u16* base = gated + (size_t)n * 12 * 256;
        #pragma unroll
        for (int m = 0; m < 12; ++m) {
            u32 uf = *reinterpret_cast<const u32*>(base + m * 256 + c0);
            u32 uc = *reinterpret_cast<const u32*>(base + m * 256 + 128 + c0);
            float f0 = bflo(uf), f1 = bfhi(uf);
            float c_0 = bflo(uc), c_1 = bfhi(uc);
            float gf0 = fmaf(f0, s1f0, t1f0), gf1 = fmaf(f1, s1f1, t1f1);
            float gc0 = fmaf(c_0, s1c0, t1c0), gc1 = fmaf(c_1, s1c1, t1c1);
            S0 += sigmoid_f(gf0) * softplus_f(gc0);
            S1 += sigmoid_f(gf1) * softplus_f(gc1);
        }
        *reinterpret_cast<float2*>(&out[(size_t)n * A_FEA + c0]) = make_float2(S0, S1);
        bs0 += S0; bq0 = fmaf(S0, S0, bq0);
        bs1 += S1; bq1 = fmaf(S1, S1, bq1);
    }

    red[aoff][lidc][0] = bs0; red[aoff][lidc][1] = bq0;
    red[aoff][lidc][2] = bs1; red[aoff][lidc][3] = bq1;
    __syncthreads();
    if (t < 64) {
        float a0 = red[0][t][0] + red[1][t][0] + red[2][t][0] + red[3][t][0];
        float a1 = red[0][t][1] + red[1][t][1] + red[2][t][1] + red[3][t][1];
        float a2 = red[0][t][2] + red[1][t][2] + red[2][t][2] + red[3][t][2];
        float a3 = red[0][t][3] + red[1][t][3] + red[2][t][3] + red[3][t][3];
        atomicAdd(&stats[S_BN2SUM + 2 * t],     a0);
        atomicAdd(&stats[S_BN2SSQ + 2 * t],     a1);
        atomicAdd(&stats[S_BN2SUM + 2 * t + 1], a2);
        atomicAdd(&stats[S_BN2SSQ + 2 * t + 1], a3);
    }
}

// =====================================================================
// MID fallback edge kernel (R10 validated): estage6 template.
// =====================================================================
#define ACT2 132               // f32 stride of act rows
#define SH6_M1 17280
#define SH6_M2 (96*ACT2*4)             // 50688

template<int MODE>
__launch_bounds__(512, 2)
__global__ void estage6(const float* __restrict__ nbr_fea,
                        const int* __restrict__ nbr_idx,
                        const u16* __restrict__ w3t,
                        const u16* __restrict__ Pb,
                        const u16* __restrict__ Qb,
                        float* __restrict__ stats,
                        float* __restrict__ out_ns) {
    constexpr int SHB = (MODE == 1) ? SH6_M1 : SH6_M2;
    __shared__ __align__(16) unsigned char shraw[SHB];
    u16* e_lds = (u16*)shraw;
    u16* p_lds = (u16*)(shraw + P_SH6);
    int* idx_lds = (int*)(shraw + I_SH6);
    float* act = (float*)shraw;
    float* red = (float*)shraw;

    const int t = threadIdx.x;
    const int w = t >> 6, l = t & 63, fr = l & 15, fq = l >> 4;
    const int gbase0 = w * 16 + fq * 4;

    short8 aw[2][2];
    #pragma unroll
    for (int kt = 0; kt < 2; ++kt)
        #pragma unroll
        for (int rt = 0; rt < 2; ++rt)
            aw[kt][rt] = *reinterpret_cast<const short8*>(
                &w3t[(((kt * 16) + w + rt * 8) * 64 + l) * 8]);

    float s1v[2][4], t1v[2][4];
    if (MODE == 2) {
        #pragma unroll
        for (int rt = 0; rt < 2; ++rt)
            #pragma unroll
            for (int j = 0; j < 4; ++j) {
                int col = gbase0 + rt * 128 + j;
                s1v[rt][j] = stats[S_S1 + col];
                t1v[rt][j] = stats[S_T1 + col];
            }
    }
    float ls[2][4] = {{0,0,0,0},{0,0,0,0}}, lq[2][4] = {{0,0,0,0},{0,0,0,0}};
    float bsum = 0.f, bssq = 0.f;

    for (int tile = blockIdx.x; tile < NTILES_E; tile += GRID_E) {
        const int r0 = tile * 96;
        const int n0a = tile * 8;

        __syncthreads();

        #pragma unroll
        for (int i = 0; i < 2; ++i) {
            int o = t + i * 512;
            if (o < 768) {
                int row = o >> 3, seg = o & 7;
                const float* src = nbr_fea + (size_t)(r0 + row) * E_FEA + seg * 8;
                float4 x0 = *reinterpret_cast<const float4*>(src);
                float4 x1 = *reinterpret_cast<const float4*>(src + 4);
                uint4 pk;
                pk.x = (u32)f2bf(x0.x) | ((u32)f2bf(x0.y) << 16);
                pk.y = (u32)f2bf(x0.z) | ((u32)f2bf(x0.w) << 16);
                pk.z = (u32)f2bf(x1.x) | ((u32)f2bf(x1.y) << 16);
                pk.w = (u32)f2bf(x1.z) | ((u32)f2bf(x1.w) << 16);
                *reinterpret_cast<uint4*>(&e_lds[row * EPAD + seg * 8]) = pk;
            }
        }
        if (t < 256) {
            int row = t >> 5, seg = t & 31;
            *reinterpret_cast<uint4*>(&p_lds[row * PPAD2 + seg * 8]) =
                *reinterpret_cast<const uint4*>(&Pb[(size_t)(n0a + row) * 256 + seg * 8]);
        } else if (t >= 416) {
            int e = t - 416;
            idx_lds[e] = nbr_idx[r0 + e];
        }
        __syncthreads();

        uint2 qv0r[6], qv1r[6];
        #pragma unroll
        for (int ct = 0; ct < 6; ++ct) {
            int edge = ct * 16 + fr;
            int jr = idx_lds[edge];
            const u16* qb = Qb + (size_t)jr * 256;
            qv0r[ct] = *reinterpret_cast<const uint2*>(qb + gbase0);
            qv1r[ct] = *reinterpret_cast<const uint2*>(qb + gbase0 + 128);
        }

        f32x4 acc[2][6];
        #pragma unroll
        for (int rt = 0; rt < 2; ++rt)
            #pragma unroll
            for (int ct = 0; ct < 6; ++ct)
                acc[rt][ct] = (f32x4){0.f,0.f,0.f,0.f};
        #pragma unroll
        for (int kt = 0; kt < 2; ++kt) {
            short8 bf[6];
            #pragma unroll
            for (int ct = 0; ct < 6; ++ct)
                bf[ct] = *reinterpret_cast<const short8*>(
                    &e_lds[(ct * 16 + fr) * EPAD + kt * 32 + fq * 8]);
            #pragma unroll
            for (int rt = 0; rt < 2; ++rt)
                #pragma unroll
                for (int ct = 0; ct < 6; ++ct)
                    acc[rt][ct] = __builtin_amdgcn_mfma_f32_16x16x32_bf16(
                        aw[kt][rt], bf[ct], acc[rt][ct], 0, 0, 0);
        }

        if (MODE == 1) {
            #pragma unroll
            for (int ct = 0; ct < 6; ++ct) {
                int edge = ct * 16 + fr;
                int atom = (edge * 171) >> 11;
                uint2 qv0 = qv0r[ct], qv1 = qv1r[ct];
                uint2 pv0 = *reinterpret_cast<const uint2*>(&p_lds[atom * PPAD2 + gbase0]);
                uint2 pv1 = *reinterpret_cast<const uint2*>(&p_lds[atom * PPAD2 + gbase0 + 128]);
                float g;
                g = acc[0][ct][0] + bflo(qv0.x) + bflo(pv0.x); ls[0][0] += g; lq[0][0] = fmaf(g,g,lq[0][0]);
                g = acc[0][ct][1] + bfhi(qv0.x) + bfhi(pv0.x); ls[0][1] += g; lq[0][1] = fmaf(g,g,lq[0][1]);
                g = acc[0][ct][2] + bflo(qv0.y) + bflo(pv0.y); ls[0][2] += g; lq[0][2] = fmaf(g,g,lq[0][2]);
                g = acc[0][ct][3] + bfhi(qv0.y) + bfhi(pv0.y); ls[0][3] += g; lq[0][3] = fmaf(g,g,lq[0][3]);
                g = acc[1][ct][0] + bflo(qv1.x) + bflo(pv1.x); ls[1][0] += g; lq[1][0] = fmaf(g,g,lq[1][0]);
                g = acc[1][ct][1] + bfhi(qv1.x) + bfhi(pv1.x); ls[1][1] += g; lq[1][1] = fmaf(g,g,lq[1][1]);
                g = acc[1][ct][2] + bflo(qv1.y) + bflo(pv1.y); ls[1][2] += g; lq[1][2] = fmaf(g,g,lq[1][2]);
                g = acc[1][ct][3] + bfhi(qv1.y) + bfhi(pv1.y); ls[1][3] += g; lq[1][3] = fmaf(g,g,lq[1][3]);
            }
        } else {
            float ar[6][4];
            #pragma unroll
            for (int ct = 0; ct < 6; ++ct) {
                int edge = ct * 16 + fr;
                int atom = (edge * 171) >> 11;
                uint2 qv0 = qv0r[ct], qv1 = qv1r[ct];
                uint2 pv0 = *reinterpret_cast<const uint2*>(&p_lds[atom * PPAD2 + gbase0]);
                uint2 pv1 = *reinterpret_cast<const uint2*>(&p_lds[atom * PPAD2 + gbase0 + 128]);
                float gf, gc;
                gf = acc[0][ct][0] + bflo(qv0.x) + bflo(pv0.x);
                gc = acc[1][ct][0] + bflo(qv1.x) + bflo(pv1.x);
                ar[ct][0] = sigmoid_f(fmaf(gf, s1v[0][0], t1v[0][0])) * softplus_f(fmaf(gc, s1v[1][0], t1v[1][0]));
                gf = acc[0][ct][1] + bfhi(qv0.x) + bfhi(pv0.x);
                gc = acc[1][ct][1] + bfhi(qv1.x) + bfhi(pv1.x);
                ar[ct][1] = sigmoid_f(fmaf(gf, s1v[0][1], t1v[0][1])) * softplus_f(fmaf(gc, s1v[1][1], t1v[1][1]));
                gf = acc[0][ct][2] + bflo(qv0.y) + bflo(pv0.y);
                gc = acc[1][ct][2] + bflo(qv1.y) + bflo(pv1.y);
                ar[ct][2] = sigmoid_f(fmaf(gf, s1v[0][2], t1v[0][2])) * softplus_f(fmaf(gc, s1v[1][2], t1v[1][2]));
                gf = acc[0][ct][3] + bfhi(qv0.y) + bfhi(pv0.y);
                gc = acc[1][ct][3] + bfhi(qv1.y) + bfhi(pv1.y);
                ar[ct][3] = sigmoid_f(fmaf(gf, s1v[0][3], t1v[0][3])) * softplus_f(fmaf(gc, s1v[1][3], t1v[1][3]));
            }
            __syncthreads();
            #pragma unroll
            for (int ct = 0; ct < 6; ++ct) {
                int edge = ct * 16 + fr;
                float4 f4 = make_float4(ar[ct][0], ar[ct][1], ar[ct][2], ar[ct][3]);
                *reinterpret_cast<float4*>(&act[edge * ACT2 + gbase0]) = f4;
            }
            __syncthreads();
            #pragma unroll
            for (int i = 0; i < 2; ++i) {
                int o = i * 512 + t;
                int a = o >> 7;
                int c = t & 127;
                float S = 0.f;
                #pragma unroll
                for (int mm = 0; mm < 12; ++mm)
                    S += act[(a * 12 + mm) * ACT2 + c];
                out_ns[(size_t)(n0a + a) * A_FEA + c] = S;
                bsum += S;
                bssq = fmaf(S, S, bssq);
            }
        }
    }

    if (MODE == 1) {
        #pragma unroll
        for (int rt = 0; rt < 2; ++rt)
            #pragma unroll
            for (int j = 0; j < 4; ++j) {
                float s = ls[rt][j], q = lq[rt][j];
                s += __shfl_xor(s, 1, 64);  s += __shfl_xor(s, 2, 64);
                s += __shfl_xor(s, 4, 64);  s += __shfl_xor(s, 8, 64);
                q += __shfl_xor(q, 1, 64);  q += __shfl_xor(q, 2, 64);
                q += __shfl_xor(q, 4, 64);  q += __shfl_xor(q, 8, 64);
                if (fr == 0) {
                    int col = gbase0 + rt * 128 + j;
                    atomicAdd(&stats[S_BN1SUM + col], s);
                    atomicAdd(&stats[S_BN1SSQ + col], q);
                }
            }
    } else {
        __syncthreads();
        if (t >= 128) {
            red[(t - 128) * 2]     = bsum;
            red[(t - 128) * 2 + 1] = bssq;
        }
        __syncthreads();
        if (t < 128) {
            bsum += red[t * 2]     + red[(128 + t) * 2]     + red[(256 + t) * 2];
            bssq += red[t * 2 + 1] + red[(128 + t) * 2 + 1] + red[(256 + t) * 2 + 1];
            atomicAdd(&stats[S_BN2SUM + t], bsum);
            atomicAdd(&stats[S_BN2SSQ + t], bssq);
        }
    }
}

// Skip GEMM + bn2 affine + softplus (in place on out).
#define BM5 64
__launch_bounds__(256, 2)
__global__ void skip_kernel(const float* __restrict__ atom_in,
                            const u16* __restrict__ wsf,
                            const float* __restrict__ b_skip,
                            const float* __restrict__ stats,
                            float* __restrict__ out) {
    __shared__ u16 a5[BM5 * 136];
    const int t = threadIdx.x;
    const int w = t >> 6, l = t & 63, fr = l & 15, fq = l >> 4;
    const int n0 = blockIdx.x * BM5;

    #pragma unroll
    for (int it = 0; it < 4; ++it) {
        int c = t + it * 256;
        int row = c >> 4, seg = c & 15;
        int n = n0 + row;
        uint4 pk = {0u, 0u, 0u, 0u};
        if (n < N_ATOM) {
            const float* src = atom_in + (size_t)n * A_FEA + seg * 8;
            float4 x0 = *reinterpret_cast<const float4*>(src);
            float4 x1 = *reinterpret_cast<const float4*>(src + 4);
            pk.x = (u32)f2bf(x0.x) | ((u32)f2bf(x0.y) << 16);
            pk.y = (u32)f2bf(x0.z) | ((u32)f2bf(x0.w) << 16);
            pk.z = (u32)f2bf(x1.x) | ((u32)f2bf(x1.y) << 16);
            pk.w = (u32)f2bf(x1.z) | ((u32)f2bf(x1.w) << 16);
        }
        *reinterpret_cast<uint4*>(&a5[row * 136 + seg * 8]) = pk;
    }
    __syncthreads();

    f32x4 acc[4][2];
    #pragma unroll
    for (int rt = 0; rt < 4; ++rt) {
        acc[rt][0] = (f32x4){0.f,0.f,0.f,0.f};
        acc[rt][1] = (f32x4){0.f,0.f,0.f,0.f};
    }
    for (int kt = 0; kt < 4; ++kt) {
        short8 af[4], bf[2];
        #pragma unroll
        for (int rt = 0; rt < 4; ++rt)
            af[rt] = *reinterpret_cast<const short8*>(
                &a5[(rt * 16 + fr) * 136 + kt * 32 + fq * 8]);
        #pragma unroll
        for (int p = 0; p < 2; ++p)
            bf[p] = *reinterpret_cast<const short8*>(
                &wsf[((kt * 8 + 2 * w + p) * 64 + l) * 8]);
        #pragma unroll
        for (int rt = 0; rt < 4; ++rt)
            #pragma unroll
            for (int p = 0; p < 2; ++p)
                acc[rt][p] = __builtin_amdgcn_mfma_f32_16x16x32_bf16(
                    af[rt], bf[p], acc[rt][p], 0, 0, 0);
    }

    #pragma unroll
    for (int p = 0; p < 2; ++p) {
        int col = w * 32 + p * 16 + fr;
        float bs = b_skip[col];
        float s2 = stats[S_S2 + col];
        float t2 = stats[S_T2 + col];
        #pragma unroll
        for (int rt = 0; rt < 4; ++rt)
            #pragma unroll
            for (int j = 0; j < 4; ++j) {
                int n = n0 + rt * 16 + fq * 4 + j;
                if (n < N_ATOM) {
                    size_t o = (size_t)n * A_FEA + col;
                    float S = out[o];
                    out[o] = softplus_f(acc[rt][p][j] + bs + fmaf(S, s2, t2));
                }
            }
    }
}

// =====================================================================
// SLOW fallback path (round-2 validated code, unchanged)
// =====================================================================
#define BM 96
#define NTILES (ROWS/BM)
#define GRID_P 2500
#define TPB 256
#define APAD 328
#define ACTPAD 132

__global__ void prep_pack_slow(const float* __restrict__ Wfull,
                               const float* __restrict__ Wskip,
                               u16* __restrict__ wf, u16* __restrict__ wsf) {
    int tid = blockIdx.x * blockDim.x + threadIdx.x;
    if (tid < 10240) {
        int l = tid & 63;
        int ct = (tid >> 6) & 15;
        int kt = tid >> 10;
        int fr = l & 15, fq = l >> 4;
        int col = ct * 16 + fr;
        int k0 = kt * 32 + fq * 8;
        u16 tmp[8];
        #pragma unroll
        for (int i = 0; i < 8; ++i) tmp[i] = f2bf(Wfull[(k0 + i) * GDIM + col]);
        uint4 pk;
        pk.x = (u32)tmp[0] | ((u32)tmp[1] << 16);
        pk.y = (u32)tmp[2] | ((u32)tmp[3] << 16);
        pk.z = (u32)tmp[4] | ((u32)tmp[5] << 16);
        pk.w = (u32)tmp[6] | ((u32)tmp[7] << 16);
        *reinterpret_cast<uint4*>(&wf[tid * 8]) = pk;
    } else if (tid < 12288) {
        int t2 = tid - 10240;
        int l = t2 & 63;
        int ct = (t2 >> 6) & 7;
        int kt = t2 >> 9;
        int fr = l & 15, fq = l >> 4;
        int col = ct * 16 + fr;
        int k0 = kt * 32 + fq * 8;
        u16 tmp[8];
        #pragma unroll
        for (int i = 0; i < 8; ++i) tmp[i] = f2bf(Wskip[(k0 + i) * A_FEA + col]);
        uint4 pk;
        pk.x = (u32)tmp[0] | ((u32)tmp[1] << 16);
        pk.y = (u32)tmp[2] | ((u32)tmp[3] << 16);
        pk.z = (u32)tmp[4] | ((u32)tmp[5] << 16);
        pk.w = (u32)tmp[6] | ((u32)tmp[7] << 16);
        *reinterpret_cast<uint4*>(&wsf[t2 * 8]) = pk;
    }
}

template<int PASS>
__launch_bounds__(TPB, 2)
__global__ void pass_kernel(const float* __restrict__ atom_in,
                            const float* __restrict__ nbr_fea,
                            const int* __restrict__ nbr_idx,
                            const u16* __restrict__ wf,
                            float* __restrict__ stats,
                            float* __restrict__ out_ns) {
    __shared__ union {
        u16 a[BM * APAD];
        float act[BM * ACTPAD];
    } sh;

    const int t = threadIdx.x;
    const int w = t >> 6, l = t & 63, fr = l & 15, fq = l >> 4;
    const int ct0 = 2 * w;

    int colp[4];
    colp[0] = ct0 * 16 + fr;
    colp[1] = colp[0] + 16;
    colp[2] = colp[0] + 128;
    colp[3] = colp[1] + 128;

    float s1v[4], t1v[4];
    if (PASS == 2) {
        #pragma unroll
        for (int p = 0; p < 4; ++p) {
            s1v[p] = stats[S_S1 + colp[p]];
            t1v[p] = stats[S_T1 + colp[p]];
        }
    }
    float ls[4] = {0.f,0.f,0.f,0.f}, lq[4] = {0.f,0.f,0.f,0.f};
    float bsum = 0.f, bssq = 0.f;

    for (int tile = blockIdx.x; tile < NTILES; tile += GRID_P) {
        const int n0 = tile * 8;

        __syncthreads();
        for (int it = 0; it < 15; ++it) {
            int c = t + it * TPB;
            int row = c / 40;
            int seg = c - row * 40;
            int an = row / 12;
            int m  = row - an * 12;
            int na = n0 + an;
            const float* src;
            if (seg < 16) {
                src = atom_in + (size_t)na * A_FEA + seg * 8;
            } else if (seg < 32) {
                int j = nbr_idx[na * M_NBR + m];
                src = atom_in + (size_t)j * A_FEA + (seg - 16) * 8;
            } else {
                src = nbr_fea + ((size_t)na * M_NBR + m) * E_FEA + (seg - 32) * 8;
            }
            float4 x0 = *reinterpret_cast<const float4*>(src);
            float4 x1 = *reinterpret_cast<const float4*>(src + 4);
            uint4 pk;
            pk.x = (u32)f2bf(x0.x) | ((u32)f2bf(x0.y) << 16);
            pk.y = (u32)f2bf(x0.z) | ((u32)f2bf(x0.w) << 16);
            pk.z = (u32)f2bf(x1.x) | ((u32)f2bf(x1.y) << 16);
            pk.w = (u32)f2bf(x1.z) | ((u32)f2bf(x1.w) << 16);
            *reinterpret_cast<uint4*>(&sh.a[row * APAD + seg * 8]) = pk;
        }
        __syncthreads();

        f32x4 acc[6][4];
        #pragma unroll
        for (int rt = 0; rt < 6; ++rt)
            #pragma unroll
            for (int p = 0; p < 4; ++p)
                acc[rt][p] = (f32x4){0.f,0.f,0.f,0.f};

        for (int kt = 0; kt < 10; ++kt) {
            short8 af[6], bf[4];
            #pragma unroll
            for (int rt = 0; rt < 6; ++rt)
                af[rt] = *reinterpret_cast<const short8*>(
                    &sh.a[(rt * 16 + fr) * APAD + kt * 32 + fq * 8]);
            #pragma unroll
            for (int p = 0; p < 4; ++p) {
                int ct = (p < 2) ? (ct0 + p) : (ct0 + 8 + (p - 2));
                bf[p] = *reinterpret_cast<const short8*>(
                    &wf[((kt * 16 + ct) * 64 + l) * 8]);
            }
            #pragma unroll
            for (int rt = 0; rt < 6; ++rt)
                #pragma unroll
                for (int p = 0; p < 4; ++p)
                    acc[rt][p] = __builtin_amdgcn_mfma_f32_16x16x32_bf16(
                        af[rt], bf[p], acc[rt][p], 0, 0, 0);
        }

        if (PASS == 1) {
            #pragma unroll
            for (int p = 0; p < 4; ++p)
                #pragma unroll
                for (int rt = 0; rt < 6; ++rt)
                    #pragma unroll
                    for (int j = 0; j < 4; ++j) {
                        float v = acc[rt][p][j];
                        ls[p] += v;
                        lq[p] = fmaf(v, v, lq[p]);
                    }
        } else {
            __syncthreads();
            #pragma unroll
            for (int rt = 0; rt < 6; ++rt)
                #pragma unroll
                for (int p = 0; p < 2; ++p)
                    #pragma unroll
                    for (int j = 0; j < 4; ++j) {
                        float gf = fmaf(acc[rt][p][j],     s1v[p],     t1v[p]);
                        float gc = fmaf(acc[rt][2 + p][j], s1v[2 + p], t1v[2 + p]);
                        float a = sigmoid_f(gf) * softplus_f(gc);
                        int row = rt * 16 + fq * 4 + j;
                        int colact = ct0 * 16 + p * 16 + fr;
                        sh.act[row * ACTPAD + colact] = a;
                    }
            __syncthreads();
            #pragma unroll
            for (int i = 0; i < 4; ++i) {
                int o = i * TPB + t;
                int a = o >> 7;
                int c = o & 127;
                float S = 0.f;
                #pragma unroll
                for (int mm = 0; mm < 12; ++mm)
                    S += sh.act[(a * 12 + mm) * ACTPAD + c];
                out_ns[(size_t)(n0 + a) * A_FEA + c] = S;
                bsum += S;
                bssq = fmaf(S, S, bssq);
            }
        }
    }

    if (PASS == 1) {
        #pragma unroll
        for (int p = 0; p < 4; ++p) {
            float s = ls[p], q = lq[p];
            s += __shfl_xor(s, 16, 64);
            s += __shfl_xor(s, 32, 64);
            q += __shfl_xor(q, 16, 64);
            q += __shfl_xor(q, 32, 64);
            if (fq == 0) {
                atomicAdd(&stats[S_BN1SUM + colp[p]], s);
                atomicAdd(&stats[S_BN1SSQ + colp[p]], q);
            }
        }
    } else {
        __syncthreads();
        if (t >= 128) {
            sh.act[(t - 128) * 2]     = bsum;
            sh.act[(t - 128) * 2 + 1] = bssq;
        }
        __syncthreads();
        if (t < 128) {
            bsum += sh.act[t * 2];
            bssq += sh.act[t * 2 + 1];
            atomicAdd(&stats[S_BN2SUM + t], bsum);
            atomicAdd(&stats[S_BN2SSQ + t], bssq);
        }
    }
}

// =====================================================================
extern "C" void kernel_launch(void* const* d_in, const int* in_sizes, int n_in,
                              void* d_out, int out_size, void* d_ws, size_t ws_size,
                              hipStream_t stream) {
    (void)in_sizes; (void)n_in; (void)out_size;
    const float* atom_in = (const float*)d_in[0];
    const float* nbr_fea = (const float*)d_in[1];
    const int*   nbr_idx = (const int*)d_in[2];
    const float* Wfull   = (const float*)d_in[3];
    // d_in[4] = b_full: cancels exactly under batchnorm1 -> unused
    const float* g1      = (const float*)d_in[5];
    const float* b1      = (const float*)d_in[6];
    const float* g2      = (const float*)d_in[7];
    const float* b2      = (const float*)d_in[8];
    const float* Wsk     = (const float*)d_in[9];
    const float* bsk     = (const float*)d_in[10];
    float* out = (float*)d_out;

    float* stats = (float*)((char*)d_ws + STATS_OFF);
    u16* wskf = (u16*)((char*)d_ws + WSK_OFF);

    if (ws_size >= NEED_FASTW) {
        u16* wpq = (u16*)d_ws;
        u16* w3t = (u16*)((char*)d_ws + W3T_OFF);
        u16* Pb  = (u16*)((char*)d_ws + P_OFF);
        u16* Qb  = (u16*)((char*)d_ws + Q_OFF);
        u16* gated = (u16*)((char*)d_ws + GATED_OFF);

        zero_stats<<<1, 256, 0, stream>>>(stats);
        prep_pack2<<<48, 256, 0, stream>>>(Wfull, Wsk, wpq, w3t, wskf);
        pq_kernel<<<(N_ATOM + 63) / 64, 256, 0, stream>>>(atom_in, wpq, Pb, Qb);
        estage7<<<GRID_E, 512, 0, stream>>>(nbr_fea, nbr_idx, w3t, Pb, Qb, stats, gated);
        finalize1<<<1, 256, 0, stream>>>(g1, b1, stats);
        apply_kernel<<<(N_ATOM + 63) / 64, 256, 0, stream>>>(gated, stats, out);
        finalize2<<<1, 128, 0, stream>>>(g2, b2, stats);
        skip_kernel<<<(N_ATOM + BM5 - 1) / BM5, 256, 0, stream>>>(atom_in, wskf, bsk, stats, out);
    } else if (ws_size >= NEED_FAST3) {
        u16* wpq = (u16*)d_ws;
        u16* w3t = (u16*)((char*)d_ws + W3T_OFF);
        u16* Pb  = (u16*)((char*)d_ws + P_OFF);
        u16* Qb  = (u16*)((char*)d_ws + Q_OFF);

        zero_stats<<<1, 256, 0, stream>>>(stats);
        prep_pack2<<<48, 256, 0, stream>>>(Wfull, Wsk, wpq, w3t, wskf);
        pq_kernel<<<(N_ATOM + 63) / 64, 256, 0, stream>>>(atom_in, wpq, Pb, Qb);
        estage6<1><<<GRID_E, 512, 0, stream>>>(nbr_fea, nbr_idx, w3t, Pb, Qb, stats, out);
        finalize1<<<1, 256, 0, stream>>>(g1, b1, stats);
        estage6<2><<<GRID_E, 512, 0, stream>>>(nbr_fea, nbr_idx, w3t, Pb, Qb, stats, out);
        finalize2<<<1, 128, 0, stream>>>(g2, b2, stats);
        skip_kernel<<<(N_ATOM + BM5 - 1) / BM5, 256, 0, stream>>>(atom_in, wskf, bsk, stats, out);
    } else {
        u16* wf = (u16*)d_ws;
        zero_stats<<<1, 256, 0, stream>>>(stats);
        prep_pack_slow<<<48, 256, 0, stream>>>(Wfull, Wsk, wf, wskf);
        pass_kernel<1><<<GRID_P, TPB, 0, stream>>>(atom_in, nbr_fea, nbr_idx, wf, stats, out);
        finalize1<<<1, 256, 0, stream>>>(g1, b1, stats);
        pass_kernel<2><<<GRID_P, TPB, 0, stream>>>(atom_in, nbr_fea, nbr_idx, wf, stats, out);
        finalize2<<<1, 128, 0, stream>>>(g2, b2, stats);
        skip_kernel<<<(N_ATOM + BM5 - 1) / BM5, 256, 0, stream>>>(atom_in, wskf, bsk, stats, out);
    }
}